// Round 4
// baseline (2102.765 us; speedup 1.0000x reference)
//
#include <hip/hip_runtime.h>

#define SEQ 4096
#define BATCH 8
#define HEADS 8
#define DMODEL 512
#define DK 64
#define PHI 128
#define CHUNK 1024
#define CROWS (CHUNK * BATCH)          // 8192 rows per chunk
#define SB 32                          // scan superblock (steps staged per barrier)
#define NSB (CHUNK / SB)               // 32

__device__ __forceinline__ void async16(const float* g, float* l)
{
    __builtin_amdgcn_global_load_lds((const __attribute__((address_space(1))) void*)g,
                                     (__attribute__((address_space(3))) void*)l, 16, 0, 0);
}
__device__ __forceinline__ void async4(const float* g, float* l)
{
    __builtin_amdgcn_global_load_lds((const __attribute__((address_space(1))) void*)g,
                                     (__attribute__((address_space(3))) void*)l, 4, 0, 0);
}

__device__ __forceinline__ float rowsum16(float x)
{
    x += __int_as_float(__builtin_amdgcn_update_dpp(0, __float_as_int(x), 0x121, 0xF, 0xF, true)); // row_ror:1
    x += __int_as_float(__builtin_amdgcn_update_dpp(0, __float_as_int(x), 0x122, 0xF, 0xF, true)); // row_ror:2
    x += __int_as_float(__builtin_amdgcn_update_dpp(0, __float_as_int(x), 0x124, 0xF, 0xF, true)); // row_ror:4
    x += __int_as_float(__builtin_amdgcn_update_dpp(0, __float_as_int(x), 0x128, 0xF, 0xF, true)); // row_ror:8
    return x;
}

// partner value x[lane ^ 32] via v_permlane32_swap (VALU pipe — no DS traffic)
__device__ __forceinline__ float xpartner32(float x)
{
#if __has_builtin(__builtin_amdgcn_permlane32_swap)
    typedef int v2i __attribute__((ext_vector_type(2)));
    v2i pr = __builtin_amdgcn_permlane32_swap(__float_as_int(x), __float_as_int(x), false, false);
    return __int_as_float((threadIdx.x & 32) ? pr.x : pr.y);
#else
    return __shfl_xor(x, 32);
#endif
}

__device__ __forceinline__ float dot8(const float4 x0, const float4 x1,
                                      const float4 y0, const float4 y1)
{
    float a  = x0.x * y0.x;
    float b2 = x1.x * y1.x;
    a = fmaf(x0.y, y0.y, a); b2 = fmaf(x1.y, y1.y, b2);
    a = fmaf(x0.z, y0.z, a); b2 = fmaf(x1.z, y1.z, b2);
    a = fmaf(x0.w, y0.w, a); b2 = fmaf(x1.w, y1.w, b2);
    return a + b2;
}

// ---------------- transpose: X[8192][512] -> XT[512][8192], 64x64 tiles ----------------
__global__ __launch_bounds__(256)
void transpose_kernel(const float* __restrict__ X, float* __restrict__ XT)
{
    __shared__ float tile[64][65];
    const int t  = threadIdx.x;
    const int tx = t & 15;
    const int ty = t >> 4;
    const int bm = blockIdx.x * 64;   // row block in X
    const int bn = blockIdx.y * 64;   // col block in X
#pragma unroll
    for (int i = 0; i < 4; ++i) {
        const int r = ty + i * 16;
        const float4 v = *(const float4*)(X + (size_t)(bm + r) * 512 + bn + tx * 4);
        tile[r][tx * 4 + 0] = v.x; tile[r][tx * 4 + 1] = v.y;
        tile[r][tx * 4 + 2] = v.z; tile[r][tx * 4 + 3] = v.w;
    }
    __syncthreads();
#pragma unroll
    for (int i = 0; i < 4; ++i) {
        const int r = ty + i * 16;    // XT row = bn + r
        float4 v;
        v.x = tile[tx * 4 + 0][r];
        v.y = tile[tx * 4 + 1][r];
        v.z = tile[tx * 4 + 2][r];
        v.w = tile[tx * 4 + 3][r];
        *(float4*)(XT + (size_t)(bn + r) * CROWS + bm + tx * 4) = v;
    }
}

// ---------------- TN GEMM: C[M=8192][N] = AT[512][8192]^T @ B[512][512] ----------------
// Tile 128(M) x 128(N), BK=16, 256 threads, 8x8 micro-tile — the LDS-balanced shape:
// 4 ds_read_b128 per 64 FMA per lane = exactly the 128 B/cyc LDS : 128 FMA/cyc VALU
// ratio. (Previous 8x4 micro was LDS-bound 1.9x: 3 b128 per 32 FMA.)
// Double-buffered async global_load_lds staging, one barrier per K-tile.
// MODE: 0 = plain store, 1 = +bias, 2 = fused dpfp (tile = TWO heads: acc[.][0..3]
// feeds head bn/64, acc[.][4..7] feeds head bn/64+1).
template <int MODE>
__global__ __launch_bounds__(256)
void gemm_tn(const float* __restrict__ AT, const float* __restrict__ B,
             const float* __restrict__ bias, float* __restrict__ C,
             int ldat, int ldc)
{
    __shared__ __align__(16) float As[2][16][128];
    __shared__ __align__(16) float Bs[2][16][128];
    const int t  = threadIdx.x;
    const int tx = t & 15;
    const int ty = t >> 4;
    const int bm = blockIdx.x * 128;
    const int bn = blockIdx.y * 128;

    float acc[8][8];
#pragma unroll
    for (int i = 0; i < 8; ++i)
#pragma unroll
        for (int j = 0; j < 8; ++j) acc[i][j] = 0.f;

    auto stage = [&](int buf, int kt) {
        const int k0 = kt * 16;
#pragma unroll
        for (int i = 0; i < 2; ++i) {        // 512 float4 each for A and B tiles
            const int L = t + i * 256;
            const int k = L >> 5, c4 = L & 31;
            async16(AT + (size_t)(k0 + k) * ldat + bm + c4 * 4,
                    &As[buf][0][0] + L * 4);
            async16(B + (size_t)(k0 + k) * 512 + bn + c4 * 4,
                    &Bs[buf][0][0] + L * 4);
        }
    };

    stage(0, 0);
    for (int kt = 0; kt < 32; ++kt) {
        const int buf = kt & 1;
        __syncthreads();                 // vmcnt drain: buf's staged loads landed
        if (kt + 1 < 32) stage(buf ^ 1, kt + 1);
#pragma unroll
        for (int k = 0; k < 16; ++k) {
            float af[8], bf[8];
            *(float4*)&af[0] = *(const float4*)&As[buf][k][ty * 8];
            *(float4*)&af[4] = *(const float4*)&As[buf][k][ty * 8 + 4];
            *(float4*)&bf[0] = *(const float4*)&Bs[buf][k][tx * 4];
            *(float4*)&bf[4] = *(const float4*)&Bs[buf][k][64 + tx * 4];
#pragma unroll
            for (int i = 0; i < 8; ++i)
#pragma unroll
                for (int j = 0; j < 8; ++j)
                    acc[i][j] = fmaf(af[i], bf[j], acc[i][j]);
        }
    }

    if (MODE == 2) {
        // fused dpfp, once per head-half. Head cols live on 16 tx-lanes x 4 each;
        // roll = one intra-16-lane shuffle; L1 norm = rowsum16 across tx.
        const int ln  = t & 63;
        const int lnp = (ln & 48) | ((ln + 15) & 15);   // same ty-row, tx-1 (mod 16)
        const int hA  = bn >> 6;                        // heads hA (cols 0..63), hA+1 (64..127)
#pragma unroll
        for (int hh = 0; hh < 2; ++hh) {
            const int h = hA + hh;
#pragma unroll
            for (int i = 0; i < 8; ++i) {
                const int m = bm + ty * 8 + i;
                float ap[4], an[4];
#pragma unroll
                for (int j = 0; j < 4; ++j) {
                    const float v = acc[i][hh * 4 + j];
                    ap[j] = fmaxf(v, 0.f);
                    an[j] = fmaxf(-v, 0.f);
                }
                const float sap = __shfl(ap[3], lnp);
                const float san = __shfl(an[3], lnp);
                const float p0  = (tx == 0) ? san : sap;    // col0 wraps to an[63]
                const float p64 = (tx == 0) ? sap : san;    // col64 wraps to ap[63]
                float y0[4], y1[4];
                y0[0] = ap[0] * p0;    y1[0] = an[0] * p64;
                y0[1] = ap[1] * ap[0]; y1[1] = an[1] * an[0];
                y0[2] = ap[2] * ap[1]; y1[2] = an[2] * an[1];
                y0[3] = ap[3] * ap[2]; y1[3] = an[3] * an[2];
                float s = (y0[0] + y0[1] + y0[2] + y0[3]) + (y1[0] + y1[1] + y1[2] + y1[3]);
                s = rowsum16(s);
                const float inv = 1.f / (s + 1e-6f);
                float4 o0, o1;
                o0.x = y0[0] * inv; o0.y = y0[1] * inv; o0.z = y0[2] * inv; o0.w = y0[3] * inv;
                o1.x = y1[0] * inv; o1.y = y1[1] * inv; o1.z = y1[2] * inv; o1.w = y1[3] * inv;
                *(float4*)(C + (size_t)m * ldc + h * 128 + tx * 4)      = o0;
                *(float4*)(C + (size_t)m * ldc + h * 128 + 64 + tx * 4) = o1;
            }
        }
    } else {
#pragma unroll
        for (int i = 0; i < 8; ++i) {
            const int m = bm + ty * 8 + i;
            float4 o0, o1;
            o0.x = acc[i][0]; o0.y = acc[i][1]; o0.z = acc[i][2]; o0.w = acc[i][3];
            o1.x = acc[i][4]; o1.y = acc[i][5]; o1.z = acc[i][6]; o1.w = acc[i][7];
            if (MODE == 1) {
                const float4 b0 = *(const float4*)(bias + bn + tx * 4);
                const float4 b1 = *(const float4*)(bias + bn + 64 + tx * 4);
                o0.x += b0.x; o0.y += b0.y; o0.z += b0.z; o0.w += b0.w;
                o1.x += b1.x; o1.y += b1.y; o1.z += b1.z; o1.w += b1.w;
            }
            *(float4*)(C + (size_t)m * ldc + bn + tx * 4)      = o0;
            *(float4*)(C + (size_t)m * ldc + bn + 64 + tx * 4) = o1;
        }
    }
}

// ---------------- gate: beta = sigmoid(x @ Wg), [32768, 8], whole sequence ----------------
__global__ __launch_bounds__(256)
void gemm_g_kernel(const float* __restrict__ X, const float* __restrict__ Wg,
                   float* __restrict__ Bt)
{
    const int idx = blockIdx.x * 256 + threadIdx.x;   // 262144 total
    const int row = idx >> 3;
    const int c   = idx & 7;
    const float4* x4 = (const float4*)(X + (size_t)row * DMODEL);
    float acc = 0.f;
    for (int k4 = 0; k4 < 128; ++k4) {
        const float4 xv = x4[k4];
        acc = fmaf(xv.x, Wg[(k4 * 4 + 0) * 8 + c], acc);
        acc = fmaf(xv.y, Wg[(k4 * 4 + 1) * 8 + c], acc);
        acc = fmaf(xv.z, Wg[(k4 * 4 + 2) * 8 + c], acc);
        acc = fmaf(xv.w, Wg[(k4 * 4 + 3) * 8 + c], acc);
    }
    Bt[idx] = 1.f / (1.f + expf(-acc));
}

// ---------------- scan ----------------
// R4 change: 32 col-lanes x 4 cols/lane (was 16 x 8) -> 512 blocks x 256 thr =
// 131072 lanes = 2 waves/SIMD (was the structural 1-wave/SIMD cap; the scan was
// latency-stall-bound: 431 cyc/step vs 164-cyc DS floor, both pipes ~40%).
// Row's 32 col-lanes laid as {0-15} U {32-47} (c' = (ln&15)|((ln&32)>>1)) so the
// cross-16 reduce is permlane32_swap — VALU pipe, zero extra DS traffic.
// 2-step look-ahead linearization (R1) and data-only kk/kq1/kq0 scalars kept.
__global__ __launch_bounds__(256)
void scan_kernel(const float* __restrict__ Qp, const float* __restrict__ Kp,
                 const float* __restrict__ Vd, const float* __restrict__ Bt,
                 float* __restrict__ outsT, float* __restrict__ Wst,
                 int s0, int first)
{
    const int blk = blockIdx.x;            // 512 blocks
    const int bh  = blk & 63;
    const int rg  = blk >> 6;              // 0..7, rows rg*8 .. rg*8+7
    const int b   = bh >> 3;
    const int h   = bh & 7;
    const int t   = threadIdx.x;
    const int wv  = t >> 6;                // wave 0..3
    const int ln  = t & 63;
    const int cp  = (ln & 15) | ((ln & 32) >> 1);   // col lane 0..31
    const int rb  = 2 * wv + ((ln >> 4) & 1);       // row within block 0..7

    __shared__ __align__(16) float sk[2][SB][PHI];
    __shared__ __align__(16) float sq[2][SB][PHI];
    __shared__ __align__(16) float sv[2][SB][8];
    __shared__ __align__(16) float sb2[2][SB];
    __shared__ __align__(16) float sd[2][SB][4];   // {kk, kq1, kq0, beta}

    const size_t bh128 = (size_t)(b * 8 + h) * 128;

    // w[0],w[1] = cols 2cp,2cp+1 ; w[2],w[3] = cols 64+2cp,64+2cp+1
    float w[4];
    float* wslot = Wst + (size_t)blk * 1024 + t * 4;
    if (first) {
#pragma unroll
        for (int j = 0; j < 4; ++j) w[j] = 0.f;
    } else {
        const float4 w0 = *(const float4*)(wslot);
        w[0] = w0.x; w[1] = w0.y; w[2] = w0.z; w[3] = w0.w;
    }

    auto stage = [&](int sbuf, int sb) {
        const int sqb = sb * SB;
        if (wv < 2) {
            // K: 1024 float4, waves 0,1 x 8 iters
#pragma unroll
            for (int i = 0; i < 8; ++i) {
                const int L  = i * 128 + wv * 64 + ln;
                const int sl = L >> 5, c4 = L & 31;
                async16(Kp + (size_t)(sqb + sl) * 8192 + bh128 + c4 * 4,
                        &sk[sbuf][0][0] + L * 4);
            }
            // V: 64 float4 (32 sl x 2), waves 0,1 lanes 0..31
            if (ln < 32) {
                const int L  = wv * 32 + ln;             // 0..63
                const int sl = L >> 1, j = L & 1;
                async16(Vd + (size_t)(sqb + sl) * 4096 + b * 512 + h * 64 + rg * 8 + j * 4,
                        &sv[sbuf][0][0] + L * 4);
            }
        } else {
            // Q: 1024 float4, waves 2,3 x 8 iters
#pragma unroll
            for (int i = 0; i < 8; ++i) {
                const int L  = i * 128 + (wv - 2) * 64 + ln;
                const int sl = L >> 5, c4 = L & 31;
                async16(Qp + (size_t)(sqb + sl) * 8192 + bh128 + c4 * 4,
                        &sq[sbuf][0][0] + L * 4);
            }
            // beta: 32 floats, wave 2 lanes 0..31
            if (wv == 2 && ln < SB) {
                async4(Bt + (size_t)(s0 + sqb + ln) * 64 + b * 8 + h,
                       &sb2[sbuf][0] + ln);
            }
        }
    };

    // -------- cooperative per-superblock dot scalars (16-lane layout, unchanged) ------
    auto dots_phase = [&](int buf, int sb) {
        const int c16  = t & 15;
        const int slot = t >> 4;                 // 0..15, steps 2*slot, 2*slot+1
        const int sl0  = 2 * slot;
        const float* kmp = (slot == 0) ? &sk[buf ^ 1][SB - 1][0] : &sk[buf][sl0 - 1][0];
        const float4 km0 = *(const float4*)(kmp + 4 * c16);
        const float4 km1 = *(const float4*)(kmp + 64 + 4 * c16);
        const float4 ka0 = *(const float4*)&sk[buf][sl0][4 * c16];
        const float4 ka1 = *(const float4*)&sk[buf][sl0][64 + 4 * c16];
        const float4 kb0 = *(const float4*)&sk[buf][sl0 + 1][4 * c16];
        const float4 kb1 = *(const float4*)&sk[buf][sl0 + 1][64 + 4 * c16];
        const float4 qa0 = *(const float4*)&sq[buf][sl0][4 * c16];
        const float4 qa1 = *(const float4*)&sq[buf][sl0][64 + 4 * c16];
        const float4 qb0 = *(const float4*)&sq[buf][sl0 + 1][4 * c16];
        const float4 qb1 = *(const float4*)&sq[buf][sl0 + 1][64 + 4 * c16];
        const float kk_a  = rowsum16(dot8(km0, km1, ka0, ka1));
        const float kq1_a = rowsum16(dot8(km0, km1, qa0, qa1));
        const float kq0_a = rowsum16(dot8(ka0, ka1, qa0, qa1));
        const float kk_b  = rowsum16(dot8(ka0, ka1, kb0, kb1));
        const float kq1_b = rowsum16(dot8(ka0, ka1, qb0, qb1));
        const float kq0_b = rowsum16(dot8(kb0, kb1, qb0, qb1));
        if (c16 == 0) {
            const bool z = (sb == 0) && (slot == 0);   // chunk's step 0: d_prev == 0
            sd[buf][sl0][0] = z ? 0.f : kk_a;
            sd[buf][sl0][1] = z ? 0.f : kq1_a;
            sd[buf][sl0][2] = kq0_a;
            sd[buf][sl0][3] = sb2[buf][sl0];
            sd[buf][sl0 + 1][0] = kk_b;
            sd[buf][sl0 + 1][1] = kq1_b;
            sd[buf][sl0 + 1][2] = kq0_b;
            sd[buf][sl0 + 1][3] = sb2[buf][sl0 + 1];
        }
    };

    struct Frag { float2 k0, k1, q0, q1; float bb, bv, kk, kq1, kq0; };
    Frag r[4];
    float d_prev = 0.f;

    auto preload = [&](Frag& f, int sbuf, int sl) {
        f.k0 = *(const float2*)&sk[sbuf][sl][2 * cp];
        f.k1 = *(const float2*)&sk[sbuf][sl][64 + 2 * cp];
        f.q0 = *(const float2*)&sq[sbuf][sl][2 * cp];
        f.q1 = *(const float2*)&sq[sbuf][sl][64 + 2 * cp];
        const float4 dd = *(const float4*)&sd[sbuf][sl][0];
        f.kk = dd.x; f.kq1 = dd.y; f.kq0 = dd.z; f.bb = dd.w;
        f.bv = f.bb * sv[sbuf][sl][rb];
    };

    // iteration g: entering w = w_{g-2}; f = frag g, fp = frag g-1
    auto step_compute = [&](const Frag& f, const Frag& fp, int g) {
        float A0 = w[0] * f.k0.x; A0 = fmaf(w[1], f.k0.y, A0);
        float A1 = w[2] * f.k1.x; A1 = fmaf(w[3], f.k1.y, A1);
        float Q0 = w[0] * f.q0.x; Q0 = fmaf(w[1], f.q0.y, Q0);
        float Q1 = w[2] * f.q1.x; Q1 = fmaf(w[3], f.q1.y, Q1);
        float Ar  = rowsum16(A0 + A1);
        Ar += xpartner32(Ar);
        float Aqr = rowsum16(Q0 + Q1);
        Aqr += xpartner32(Aqr);
        // lagged state update: w_{g-2} -> w_{g-1}
        w[0] = fmaf(d_prev, fp.k0.x, w[0]);
        w[1] = fmaf(d_prev, fp.k0.y, w[1]);
        w[2] = fmaf(d_prev, fp.k1.x, w[2]);
        w[3] = fmaf(d_prev, fp.k1.y, w[3]);
        // serial chain: d_{g-1} -> a_g -> d_g
        const float a = fmaf(d_prev, f.kk, Ar);
        const float d = fmaf(-f.bb, a, f.bv);
        float o = fmaf(d_prev, f.kq1, Aqr);
        o = fmaf(d, f.kq0, o);
        if (cp == 0)
            outsT[(size_t)(h * DK + rg * 8 + rb) * CROWS + g * BATCH + b] = o;
        d_prev = d;
    };

    // frag-(-1) k must be 0 (multiplied by d_prev=0; avoid NaN from stale regs)
    r[3].k0 = make_float2(0.f, 0.f);
    r[3].k1 = make_float2(0.f, 0.f);

    stage(0, 0);
    for (int sb = 0; sb < NSB; ++sb) {
        const int buf = sb & 1;
        __syncthreads();                     // staged loads for buf complete (vmcnt drain)
        dots_phase(buf, sb);
        __syncthreads();                     // sd visible; prev-buffer boundary reads done
        if (sb + 1 < NSB) stage(buf ^ 1, sb + 1);
        preload(r[0], buf, 0);
        preload(r[1], buf, 1);
#pragma unroll
        for (int s = 0; s < SB; ++s) {
            if (s + 2 < SB) preload(r[(s + 2) & 3], buf, s + 2);
            step_compute(r[s & 3], r[(s + 3) & 3], sb * SB + s);
        }
    }

    // apply the pending final update (frag 1023 lives in slot 3)
    w[0] = fmaf(d_prev, r[3].k0.x, w[0]);
    w[1] = fmaf(d_prev, r[3].k0.y, w[1]);
    w[2] = fmaf(d_prev, r[3].k1.x, w[2]);
    w[3] = fmaf(d_prev, r[3].k1.y, w[3]);

    float4 w0;
    w0.x = w[0]; w0.y = w[1]; w0.z = w[2]; w0.w = w[3];
    *(float4*)(wslot) = w0;
}

extern "C" void kernel_launch(void* const* d_in, const int* in_sizes, int n_in,
                              void* d_out, int out_size, void* d_ws, size_t ws_size,
                              hipStream_t stream)
{
    const float* x  = (const float*)d_in[0];
    const float* Wq = (const float*)d_in[1];
    const float* Wk = (const float*)d_in[2];
    const float* Wv = (const float*)d_in[3];
    const float* Wg = (const float*)d_in[4];
    const float* Wo = (const float*)d_in[5];
    const float* bo = (const float*)d_in[6];
    float* out = (float*)d_out;

    // workspace (floats), ~104 MB total. XTc (x^T per chunk) ALIASES tmp (scan outsT):
    // per chunk: transpose->XTc | QKV GEMMs read XTc | scan writes tmp | Wo GEMM reads
    // tmp | next chunk's transpose overwrites — stream-ordered, no overlap.
    float* ws  = (float*)d_ws;
    float* XTc = ws;                                   // [512][8192]  (= tmp)
    float* tmp = ws;                                   // [512][8192]  (scan outsT)
    float* Qp  = ws  + (size_t)512 * CROWS;            // [8192][1024]
    float* Kp  = Qp  + (size_t)CROWS * 1024;           // [8192][1024]
    float* Vd  = Kp  + (size_t)CROWS * 1024;           // [8192][512]
    float* Bt  = Vd  + (size_t)CROWS * 512;            // [32768][8]
    float* Wst = Bt  + (size_t)(SEQ * BATCH) * 8;      // [512][1024]
    (void)in_sizes; (void)n_in; (void)out_size; (void)ws_size;

    const dim3 gt(CROWS / 64, DMODEL / 64);    // (128, 8) transpose grid
    const dim3 gg(CROWS / 128, DMODEL / 128);  // (64, 4) = 256 workgroups
    const int NCH = SEQ / CHUNK;               // 4

    gemm_g_kernel<<<(SEQ * BATCH * 8) / 256, 256, 0, stream>>>(x, Wg, Bt);

    for (int c = 0; c < NCH; ++c) {
        const float* xc = x + (size_t)c * CROWS * DMODEL;
        transpose_kernel<<<gt, 256, 0, stream>>>(xc, XTc);
        gemm_tn<2><<<gg, 256, 0, stream>>>(XTc, Wq, nullptr, Qp, CROWS, 1024);
        gemm_tn<2><<<gg, 256, 0, stream>>>(XTc, Wk, nullptr, Kp, CROWS, 1024);
        gemm_tn<0><<<gg, 256, 0, stream>>>(XTc, Wv, nullptr, Vd, CROWS, 512);
        scan_kernel<<<512, 256, 0, stream>>>(Qp, Kp, Vd, Bt, tmp, Wst,
                                             c * CHUNK, c == 0 ? 1 : 0);
        gemm_tn<1><<<gg, 256, 0, stream>>>(tmp, Wo, bo,
                                           out + (size_t)c * CROWS * DMODEL,
                                           CROWS, 512);
    }
}

// Round 5
// 1654.663 us; speedup vs baseline: 1.2708x; 1.2708x over previous
//
#include <hip/hip_runtime.h>

#define SEQ 4096
#define BATCH 8
#define HEADS 8
#define DMODEL 512
#define DK 64
#define PHI 128
#define CHUNK 1024
#define CROWS (CHUNK * BATCH)          // 8192 rows per chunk
#define SB 32                          // scan superblock (steps staged per barrier)
#define NSB (CHUNK / SB)               // 32

__device__ __forceinline__ void async16(const float* g, float* l)
{
    __builtin_amdgcn_global_load_lds((const __attribute__((address_space(1))) void*)g,
                                     (__attribute__((address_space(3))) void*)l, 16, 0, 0);
}
__device__ __forceinline__ void async4(const float* g, float* l)
{
    __builtin_amdgcn_global_load_lds((const __attribute__((address_space(1))) void*)g,
                                     (__attribute__((address_space(3))) void*)l, 4, 0, 0);
}

__device__ __forceinline__ float rowsum16(float x)
{
    x += __int_as_float(__builtin_amdgcn_update_dpp(0, __float_as_int(x), 0x121, 0xF, 0xF, true)); // row_ror:1
    x += __int_as_float(__builtin_amdgcn_update_dpp(0, __float_as_int(x), 0x122, 0xF, 0xF, true)); // row_ror:2
    x += __int_as_float(__builtin_amdgcn_update_dpp(0, __float_as_int(x), 0x124, 0xF, 0xF, true)); // row_ror:4
    x += __int_as_float(__builtin_amdgcn_update_dpp(0, __float_as_int(x), 0x128, 0xF, 0xF, true)); // row_ror:8
    return x;
}

__device__ __forceinline__ float dot8(const float4 x0, const float4 x1,
                                      const float4 y0, const float4 y1)
{
    float a  = x0.x * y0.x;
    float b2 = x1.x * y1.x;
    a = fmaf(x0.y, y0.y, a); b2 = fmaf(x1.y, y1.y, b2);
    a = fmaf(x0.z, y0.z, a); b2 = fmaf(x1.z, y1.z, b2);
    a = fmaf(x0.w, y0.w, a); b2 = fmaf(x1.w, y1.w, b2);
    return a + b2;
}

// ---------------- transpose: X[8192][512] -> XT[512][8192], 64x64 tiles ----------------
__global__ __launch_bounds__(256)
void transpose_kernel(const float* __restrict__ X, float* __restrict__ XT)
{
    __shared__ float tile[64][65];
    const int t  = threadIdx.x;
    const int tx = t & 15;
    const int ty = t >> 4;
    const int bm = blockIdx.x * 64;   // row block in X
    const int bn = blockIdx.y * 64;   // col block in X
#pragma unroll
    for (int i = 0; i < 4; ++i) {
        const int r = ty + i * 16;
        const float4 v = *(const float4*)(X + (size_t)(bm + r) * 512 + bn + tx * 4);
        tile[r][tx * 4 + 0] = v.x; tile[r][tx * 4 + 1] = v.y;
        tile[r][tx * 4 + 2] = v.z; tile[r][tx * 4 + 3] = v.w;
    }
    __syncthreads();
#pragma unroll
    for (int i = 0; i < 4; ++i) {
        const int r = ty + i * 16;    // XT row = bn + r
        float4 v;
        v.x = tile[tx * 4 + 0][r];
        v.y = tile[tx * 4 + 1][r];
        v.z = tile[tx * 4 + 2][r];
        v.w = tile[tx * 4 + 3][r];
        *(float4*)(XT + (size_t)(bn + r) * CROWS + bm + tx * 4) = v;
    }
}

// -------- fused QKV TN GEMM: [8192,1536] = XT^T @ [Wq|Wk|Wv], 128x128 tiles --------
// grid (64, 12) = 768 blocks = 3 blocks/CU = 3 waves/SIMD — this is what R4's
// 128x128 lacked (1 block/CU left barrier drains uncovered). 8x8 micro-tile is
// DS/VALU balanced: per SIMD-round, DS = 12 waves x 4 b128 x 8 cyc = 384 cyc vs
// VALU = 3 waves x 128 cyc = 384 cyc. 32 KB LDS/block x 3 = 96 KB/CU.
// blockIdx.y: 0-3 -> Q (dpfp epilogue, 2 heads/tile), 4-7 -> K (dpfp), 8-11 -> V.
__global__ __launch_bounds__(256)
void gemm_qkv(const float* __restrict__ AT,
              const float* __restrict__ Wq, const float* __restrict__ Wk,
              const float* __restrict__ Wv,
              float* __restrict__ Qp, float* __restrict__ Kp, float* __restrict__ Vd)
{
    __shared__ __align__(16) float As[2][16][128];
    __shared__ __align__(16) float Bs[2][16][128];
    const int t  = threadIdx.x;
    const int tx = t & 15;
    const int ty = t >> 4;
    const int bm  = blockIdx.x * 128;
    const int grp = blockIdx.y >> 2;           // 0=Q, 1=K, 2=V
    const int bn  = (blockIdx.y & 3) * 128;
    const float* B = (grp == 0) ? Wq : (grp == 1) ? Wk : Wv;

    float acc[8][8];
#pragma unroll
    for (int i = 0; i < 8; ++i)
#pragma unroll
        for (int j = 0; j < 8; ++j) acc[i][j] = 0.f;

    auto stage = [&](int buf, int kt) {
        const int k0 = kt * 16;
#pragma unroll
        for (int i = 0; i < 2; ++i) {        // 512 float4 each for A and B tiles
            const int L = t + i * 256;
            const int k = L >> 5, c4 = L & 31;
            async16(AT + (size_t)(k0 + k) * CROWS + bm + c4 * 4,
                    &As[buf][0][0] + L * 4);
            async16(B + (size_t)(k0 + k) * 512 + bn + c4 * 4,
                    &Bs[buf][0][0] + L * 4);
        }
    };

    stage(0, 0);
    for (int kt = 0; kt < 32; ++kt) {
        const int buf = kt & 1;
        __syncthreads();                 // vmcnt drain: buf's staged loads landed
        if (kt + 1 < 32) stage(buf ^ 1, kt + 1);
#pragma unroll
        for (int k = 0; k < 16; ++k) {
            float af[8], bf[8];
            *(float4*)&af[0] = *(const float4*)&As[buf][k][ty * 8];
            *(float4*)&af[4] = *(const float4*)&As[buf][k][ty * 8 + 4];
            *(float4*)&bf[0] = *(const float4*)&Bs[buf][k][tx * 4];
            *(float4*)&bf[4] = *(const float4*)&Bs[buf][k][64 + tx * 4];
#pragma unroll
            for (int i = 0; i < 8; ++i)
#pragma unroll
                for (int j = 0; j < 8; ++j)
                    acc[i][j] = fmaf(af[i], bf[j], acc[i][j]);
        }
    }

    if (grp < 2) {
        // fused dpfp per head-half (R4-validated). Head cols on 16 tx-lanes x 4;
        // roll = one intra-16-lane shuffle; L1 norm = rowsum16 across tx.
        float* dst = grp ? Kp : Qp;
        const int ln  = t & 63;
        const int lnp = (ln & 48) | ((ln + 15) & 15);   // same ty-row, tx-1 (mod 16)
        const int hA  = bn >> 6;
#pragma unroll
        for (int hh = 0; hh < 2; ++hh) {
            const int h = hA + hh;
#pragma unroll
            for (int i = 0; i < 8; ++i) {
                const int m = bm + ty * 8 + i;
                float ap[4], an[4];
#pragma unroll
                for (int j = 0; j < 4; ++j) {
                    const float v = acc[i][hh * 4 + j];
                    ap[j] = fmaxf(v, 0.f);
                    an[j] = fmaxf(-v, 0.f);
                }
                const float sap = __shfl(ap[3], lnp);
                const float san = __shfl(an[3], lnp);
                const float p0  = (tx == 0) ? san : sap;    // col0 wraps to an[63]
                const float p64 = (tx == 0) ? sap : san;    // col64 wraps to ap[63]
                float y0[4], y1[4];
                y0[0] = ap[0] * p0;    y1[0] = an[0] * p64;
                y0[1] = ap[1] * ap[0]; y1[1] = an[1] * an[0];
                y0[2] = ap[2] * ap[1]; y1[2] = an[2] * an[1];
                y0[3] = ap[3] * ap[2]; y1[3] = an[3] * an[2];
                float s = (y0[0] + y0[1] + y0[2] + y0[3]) + (y1[0] + y1[1] + y1[2] + y1[3]);
                s = rowsum16(s);
                const float inv = 1.f / (s + 1e-6f);
                float4 o0, o1;
                o0.x = y0[0] * inv; o0.y = y0[1] * inv; o0.z = y0[2] * inv; o0.w = y0[3] * inv;
                o1.x = y1[0] * inv; o1.y = y1[1] * inv; o1.z = y1[2] * inv; o1.w = y1[3] * inv;
                *(float4*)(dst + (size_t)m * 1024 + h * 128 + tx * 4)      = o0;
                *(float4*)(dst + (size_t)m * 1024 + h * 128 + 64 + tx * 4) = o1;
            }
        }
    } else {
#pragma unroll
        for (int i = 0; i < 8; ++i) {
            const int m = bm + ty * 8 + i;
            float4 o0, o1;
            o0.x = acc[i][0]; o0.y = acc[i][1]; o0.z = acc[i][2]; o0.w = acc[i][3];
            o1.x = acc[i][4]; o1.y = acc[i][5]; o1.z = acc[i][6]; o1.w = acc[i][7];
            *(float4*)(Vd + (size_t)m * 512 + bn + tx * 4)      = o0;
            *(float4*)(Vd + (size_t)m * 512 + bn + 64 + tx * 4) = o1;
        }
    }
}

// ---------------- TN GEMM for Wo: C[8192][512] = outsT^T @ Wo + bo ----------------
// R3-proven shape: 128x64 tile, 8x4 micro, 512 blocks = 2 blocks/CU.
__global__ __launch_bounds__(256)
void gemm_wo(const float* __restrict__ AT, const float* __restrict__ B,
             const float* __restrict__ bias, float* __restrict__ C)
{
    __shared__ __align__(16) float As[2][16][128];
    __shared__ __align__(16) float Bs[2][16][64];
    const int t  = threadIdx.x;
    const int tx = t & 15;
    const int ty = t >> 4;
    const int bm = blockIdx.x * 128;
    const int bn = blockIdx.y * 64;

    float acc[8][4];
#pragma unroll
    for (int i = 0; i < 8; ++i)
#pragma unroll
        for (int j = 0; j < 4; ++j) acc[i][j] = 0.f;

    auto stage = [&](int buf, int kt) {
        const int k0 = kt * 16;
#pragma unroll
        for (int i = 0; i < 2; ++i) {
            const int L = t + i * 256;
            const int k = L >> 5, c4 = L & 31;
            async16(AT + (size_t)(k0 + k) * CROWS + bm + c4 * 4,
                    &As[buf][0][0] + L * 4);
        }
        {
            const int k = t >> 4, c4 = t & 15;
            async16(B + (size_t)(k0 + k) * 512 + bn + c4 * 4,
                    &Bs[buf][0][0] + t * 4);
        }
    };

    stage(0, 0);
    for (int kt = 0; kt < 32; ++kt) {
        const int buf = kt & 1;
        __syncthreads();
        if (kt + 1 < 32) stage(buf ^ 1, kt + 1);
#pragma unroll
        for (int k = 0; k < 16; ++k) {
            float af[8], bf[4];
            *(float4*)&af[0] = *(const float4*)&As[buf][k][ty * 8];
            *(float4*)&af[4] = *(const float4*)&As[buf][k][ty * 8 + 4];
            *(float4*)&bf[0] = *(const float4*)&Bs[buf][k][tx * 4];
#pragma unroll
            for (int i = 0; i < 8; ++i)
#pragma unroll
                for (int j = 0; j < 4; ++j)
                    acc[i][j] = fmaf(af[i], bf[j], acc[i][j]);
        }
    }

#pragma unroll
    for (int i = 0; i < 8; ++i) {
        const int m = bm + ty * 8 + i;
        float4 o;
        o.x = acc[i][0]; o.y = acc[i][1]; o.z = acc[i][2]; o.w = acc[i][3];
        const float4 bb = *(const float4*)(bias + bn + tx * 4);
        o.x += bb.x; o.y += bb.y; o.z += bb.z; o.w += bb.w;
        *(float4*)(C + (size_t)m * 512 + bn + tx * 4) = o;
    }
}

// ---------------- gate: beta = sigmoid(x @ Wg), [32768, 8], whole sequence ----------------
__global__ __launch_bounds__(256)
void gemm_g_kernel(const float* __restrict__ X, const float* __restrict__ Wg,
                   float* __restrict__ Bt)
{
    const int idx = blockIdx.x * 256 + threadIdx.x;   // 262144 total
    const int row = idx >> 3;
    const int c   = idx & 7;
    const float4* x4 = (const float4*)(X + (size_t)row * DMODEL);
    float acc = 0.f;
    for (int k4 = 0; k4 < 128; ++k4) {
        const float4 xv = x4[k4];
        acc = fmaf(xv.x, Wg[(k4 * 4 + 0) * 8 + c], acc);
        acc = fmaf(xv.y, Wg[(k4 * 4 + 1) * 8 + c], acc);
        acc = fmaf(xv.z, Wg[(k4 * 4 + 2) * 8 + c], acc);
        acc = fmaf(xv.w, Wg[(k4 * 4 + 3) * 8 + c], acc);
    }
    Bt[idx] = 1.f / (1.f + expf(-acc));
}

// ---------------- scan (R3-proven layout: 16 rows x 16 col-lanes, 256 blocks) ----------
// R4's 32-col-lane variant doubled total VALU work (per-lane fixed overhead doesn't
// shrink with cols/lane) — reverted. 2-step look-ahead linearization + packed sd kept.
__global__ __launch_bounds__(256)
void scan_kernel(const float* __restrict__ Qp, const float* __restrict__ Kp,
                 const float* __restrict__ Vd, const float* __restrict__ Bt,
                 float* __restrict__ outsT, float* __restrict__ Wst,
                 int s0, int first)
{
    const int blk = blockIdx.x;
    const int bh  = blk & 63;
    const int rg  = blk >> 6;
    const int b   = bh >> 3;
    const int h   = bh & 7;
    const int t   = threadIdx.x;
    const int c      = t & 15;     // col lane
    const int rloc   = t >> 4;     // row within group of 16
    const int wv  = t >> 6;        // wave id 0..3
    const int ln  = t & 63;        // lane within wave

    __shared__ __align__(16) float sk[2][SB][PHI];
    __shared__ __align__(16) float sq[2][SB][PHI];
    __shared__ __align__(16) float sv[2][SB][16];
    __shared__ __align__(16) float sb2[2][SB];
    __shared__ __align__(16) float sd[2][SB][4];   // {kk, kq1, kq0, beta}

    const size_t bh128 = (size_t)(b * 8 + h) * 128;

    float w[8];
    float* wslot = Wst + (size_t)blk * 2048 + t * 8;
    if (first) {
#pragma unroll
        for (int j = 0; j < 8; ++j) w[j] = 0.f;
    } else {
        const float4 w0 = *(const float4*)(wslot);
        const float4 w1 = *(const float4*)(wslot + 4);
        w[0] = w0.x; w[1] = w0.y; w[2] = w0.z; w[3] = w0.w;
        w[4] = w1.x; w[5] = w1.y; w[6] = w1.z; w[7] = w1.w;
    }

    auto stage = [&](int sbuf, int sb) {
        const int sqb = sb * SB;
        if (wv < 2) {
#pragma unroll
            for (int i = 0; i < 8; ++i) {
                const int L  = i * 128 + wv * 64 + ln;
                const int sl = L >> 5, c4 = L & 31;
                async16(Kp + (size_t)(sqb + sl) * 8192 + bh128 + c4 * 4,
                        &sk[sbuf][0][0] + L * 4);
            }
            {
                const int L  = wv * 64 + ln;
                const int sl = L >> 2, c4 = L & 3;
                async16(Vd + (size_t)(sqb + sl) * 4096 + b * 512 + h * 64 + rg * 16 + c4 * 4,
                        &sv[sbuf][0][0] + L * 4);
            }
        } else {
#pragma unroll
            for (int i = 0; i < 8; ++i) {
                const int L  = i * 128 + (wv - 2) * 64 + ln;
                const int sl = L >> 5, c4 = L & 31;
                async16(Qp + (size_t)(sqb + sl) * 8192 + bh128 + c4 * 4,
                        &sq[sbuf][0][0] + L * 4);
            }
            if (wv == 2 && ln < SB) {
                async4(Bt + (size_t)(s0 + sqb + ln) * 64 + b * 8 + h,
                       &sb2[sbuf][0] + ln);
            }
        }
    };

    auto dots_phase = [&](int buf, int sb) {
        const int sl0 = 2 * rloc;
        const float* kmp = (rloc == 0) ? &sk[buf ^ 1][SB - 1][0] : &sk[buf][sl0 - 1][0];
        const float4 km0 = *(const float4*)(kmp + 4 * c);
        const float4 km1 = *(const float4*)(kmp + 64 + 4 * c);
        const float4 ka0 = *(const float4*)&sk[buf][sl0][4 * c];
        const float4 ka1 = *(const float4*)&sk[buf][sl0][64 + 4 * c];
        const float4 kb0 = *(const float4*)&sk[buf][sl0 + 1][4 * c];
        const float4 kb1 = *(const float4*)&sk[buf][sl0 + 1][64 + 4 * c];
        const float4 qa0 = *(const float4*)&sq[buf][sl0][4 * c];
        const float4 qa1 = *(const float4*)&sq[buf][sl0][64 + 4 * c];
        const float4 qb0 = *(const float4*)&sq[buf][sl0 + 1][4 * c];
        const float4 qb1 = *(const float4*)&sq[buf][sl0 + 1][64 + 4 * c];
        const float kk_a  = rowsum16(dot8(km0, km1, ka0, ka1));
        const float kq1_a = rowsum16(dot8(km0, km1, qa0, qa1));
        const float kq0_a = rowsum16(dot8(ka0, ka1, qa0, qa1));
        const float kk_b  = rowsum16(dot8(ka0, ka1, kb0, kb1));
        const float kq1_b = rowsum16(dot8(ka0, ka1, qb0, qb1));
        const float kq0_b = rowsum16(dot8(kb0, kb1, qb0, qb1));
        if (c == 0) {
            const bool z = (sb == 0) && (rloc == 0);   // chunk's step 0: d_prev == 0
            sd[buf][sl0][0] = z ? 0.f : kk_a;
            sd[buf][sl0][1] = z ? 0.f : kq1_a;
            sd[buf][sl0][2] = kq0_a;
            sd[buf][sl0][3] = sb2[buf][sl0];
            sd[buf][sl0 + 1][0] = kk_b;
            sd[buf][sl0 + 1][1] = kq1_b;
            sd[buf][sl0 + 1][2] = kq0_b;
            sd[buf][sl0 + 1][3] = sb2[buf][sl0 + 1];
        }
    };

    struct Frag { float4 k0, k1, q0, q1; float bb, bv, kk, kq1, kq0; };
    Frag r[4];
    float d_prev = 0.f;

    auto preload = [&](Frag& f, int sbuf, int sl) {
        f.k0 = *(const float4*)&sk[sbuf][sl][4 * c];
        f.k1 = *(const float4*)&sk[sbuf][sl][64 + 4 * c];
        f.q0 = *(const float4*)&sq[sbuf][sl][4 * c];
        f.q1 = *(const float4*)&sq[sbuf][sl][64 + 4 * c];
        const float4 dd = *(const float4*)&sd[sbuf][sl][0];
        f.kk = dd.x; f.kq1 = dd.y; f.kq0 = dd.z; f.bb = dd.w;
        f.bv = f.bb * sv[sbuf][sl][rloc];
    };

    auto step_compute = [&](const Frag& f, const Frag& fp, int g) {
        float A0 = w[0] * f.k0.x;
        float A1 = w[4] * f.k1.x;
        A0 = fmaf(w[1], f.k0.y, A0); A1 = fmaf(w[5], f.k1.y, A1);
        A0 = fmaf(w[2], f.k0.z, A0); A1 = fmaf(w[6], f.k1.z, A1);
        A0 = fmaf(w[3], f.k0.w, A0); A1 = fmaf(w[7], f.k1.w, A1);
        float Q0 = w[0] * f.q0.x;
        float Q1 = w[4] * f.q1.x;
        Q0 = fmaf(w[1], f.q0.y, Q0); Q1 = fmaf(w[5], f.q1.y, Q1);
        Q0 = fmaf(w[2], f.q0.z, Q0); Q1 = fmaf(w[6], f.q1.z, Q1);
        Q0 = fmaf(w[3], f.q0.w, Q0); Q1 = fmaf(w[7], f.q1.w, Q1);
        const float Ar  = rowsum16(A0 + A1);
        const float Aqr = rowsum16(Q0 + Q1);
        w[0] = fmaf(d_prev, fp.k0.x, w[0]);
        w[1] = fmaf(d_prev, fp.k0.y, w[1]);
        w[2] = fmaf(d_prev, fp.k0.z, w[2]);
        w[3] = fmaf(d_prev, fp.k0.w, w[3]);
        w[4] = fmaf(d_prev, fp.k1.x, w[4]);
        w[5] = fmaf(d_prev, fp.k1.y, w[5]);
        w[6] = fmaf(d_prev, fp.k1.z, w[6]);
        w[7] = fmaf(d_prev, fp.k1.w, w[7]);
        const float a = fmaf(d_prev, f.kk, Ar);
        const float d = fmaf(-f.bb, a, f.bv);
        float o = fmaf(d_prev, f.kq1, Aqr);
        o = fmaf(d, f.kq0, o);
        if (c == 0)
            outsT[(size_t)(h * DK + rg * 16 + rloc) * CROWS + g * BATCH + b] = o;
        d_prev = d;
    };

    r[3].k0 = make_float4(0.f, 0.f, 0.f, 0.f);
    r[3].k1 = make_float4(0.f, 0.f, 0.f, 0.f);

    stage(0, 0);
    for (int sb = 0; sb < NSB; ++sb) {
        const int buf = sb & 1;
        __syncthreads();                     // staged loads for buf complete
        dots_phase(buf, sb);
        __syncthreads();                     // sd visible; prev-buffer boundary reads done
        if (sb + 1 < NSB) stage(buf ^ 1, sb + 1);
        preload(r[0], buf, 0);
        preload(r[1], buf, 1);
#pragma unroll
        for (int s = 0; s < SB; ++s) {
            if (s + 2 < SB) preload(r[(s + 2) & 3], buf, s + 2);
            step_compute(r[s & 3], r[(s + 3) & 3], sb * SB + s);
        }
    }

    // apply the pending final update (frag 1023 lives in slot 3)
    w[0] = fmaf(d_prev, r[3].k0.x, w[0]);
    w[1] = fmaf(d_prev, r[3].k0.y, w[1]);
    w[2] = fmaf(d_prev, r[3].k0.z, w[2]);
    w[3] = fmaf(d_prev, r[3].k0.w, w[3]);
    w[4] = fmaf(d_prev, r[3].k1.x, w[4]);
    w[5] = fmaf(d_prev, r[3].k1.y, w[5]);
    w[6] = fmaf(d_prev, r[3].k1.z, w[6]);
    w[7] = fmaf(d_prev, r[3].k1.w, w[7]);

    float4 w0, w1;
    w0.x = w[0]; w0.y = w[1]; w0.z = w[2]; w0.w = w[3];
    w1.x = w[4]; w1.y = w[5]; w1.z = w[6]; w1.w = w[7];
    *(float4*)(wslot)     = w0;
    *(float4*)(wslot + 4) = w1;
}

extern "C" void kernel_launch(void* const* d_in, const int* in_sizes, int n_in,
                              void* d_out, int out_size, void* d_ws, size_t ws_size,
                              hipStream_t stream)
{
    const float* x  = (const float*)d_in[0];
    const float* Wq = (const float*)d_in[1];
    const float* Wk = (const float*)d_in[2];
    const float* Wv = (const float*)d_in[3];
    const float* Wg = (const float*)d_in[4];
    const float* Wo = (const float*)d_in[5];
    const float* bo = (const float*)d_in[6];
    float* out = (float*)d_out;

    // workspace (floats), ~99 MB. XTc (x^T per chunk) ALIASES tmp (scan outsT):
    // per chunk: transpose->XTc | QKV GEMM reads XTc | scan writes tmp | Wo GEMM
    // reads tmp | next chunk's transpose overwrites — stream-ordered, no overlap.
    float* ws  = (float*)d_ws;
    float* XTc = ws;                                   // [512][8192]  (= tmp)
    float* tmp = ws;                                   // [512][8192]  (scan outsT)
    float* Qp  = ws  + (size_t)512 * CROWS;            // [8192][1024]
    float* Kp  = Qp  + (size_t)CROWS * 1024;           // [8192][1024]
    float* Vd  = Kp  + (size_t)CROWS * 1024;           // [8192][512]
    float* Bt  = Vd  + (size_t)CROWS * 512;            // [32768][8]
    float* Wst = Bt  + (size_t)(SEQ * BATCH) * 8;      // [256][2048]
    (void)in_sizes; (void)n_in; (void)out_size; (void)ws_size;

    const dim3 gt(CROWS / 64, DMODEL / 64);    // (128, 8) transpose grid
    const dim3 gq(CROWS / 128, 12);            // (64, 12) = 768 blocks fused QKV
    const dim3 go(CROWS / 128, DMODEL / 64);   // (64, 8)  = 512 blocks Wo
    const int NCH = SEQ / CHUNK;               // 4

    gemm_g_kernel<<<(SEQ * BATCH * 8) / 256, 256, 0, stream>>>(x, Wg, Bt);

    for (int c = 0; c < NCH; ++c) {
        const float* xc = x + (size_t)c * CROWS * DMODEL;
        transpose_kernel<<<gt, 256, 0, stream>>>(xc, XTc);
        gemm_qkv<<<gq, 256, 0, stream>>>(XTc, Wq, Wk, Wv, Qp, Kp, Vd);
        scan_kernel<<<256, 256, 0, stream>>>(Qp, Kp, Vd, Bt, tmp, Wst,
                                             c * CHUNK, c == 0 ? 1 : 0);
        gemm_wo<<<go, 256, 0, stream>>>(tmp, Wo, bo,
                                        out + (size_t)c * CROWS * DMODEL);
    }
}

// Round 6
// 1614.608 us; speedup vs baseline: 1.3023x; 1.0248x over previous
//
#include <hip/hip_runtime.h>

#define SEQ 4096
#define BATCH 8
#define HEADS 8
#define DMODEL 512
#define DK 64
#define PHI 128
#define CHUNK 1024
#define CROWS (CHUNK * BATCH)          // 8192 rows per chunk
#define SB 32                          // scan superblock (steps staged per barrier)
#define NSB (CHUNK / SB)               // 32

__device__ __forceinline__ void async16(const float* g, float* l)
{
    __builtin_amdgcn_global_load_lds((const __attribute__((address_space(1))) void*)g,
                                     (__attribute__((address_space(3))) void*)l, 16, 0, 0);
}
__device__ __forceinline__ void async4(const float* g, float* l)
{
    __builtin_amdgcn_global_load_lds((const __attribute__((address_space(1))) void*)g,
                                     (__attribute__((address_space(3))) void*)l, 4, 0, 0);
}

__device__ __forceinline__ float rowsum16(float x)
{
    x += __int_as_float(__builtin_amdgcn_update_dpp(0, __float_as_int(x), 0x121, 0xF, 0xF, true)); // row_ror:1
    x += __int_as_float(__builtin_amdgcn_update_dpp(0, __float_as_int(x), 0x122, 0xF, 0xF, true)); // row_ror:2
    x += __int_as_float(__builtin_amdgcn_update_dpp(0, __float_as_int(x), 0x124, 0xF, 0xF, true)); // row_ror:4
    x += __int_as_float(__builtin_amdgcn_update_dpp(0, __float_as_int(x), 0x128, 0xF, 0xF, true)); // row_ror:8
    return x;
}

__device__ __forceinline__ float dot8(const float4 x0, const float4 x1,
                                      const float4 y0, const float4 y1)
{
    float a  = x0.x * y0.x;
    float b2 = x1.x * y1.x;
    a = fmaf(x0.y, y0.y, a); b2 = fmaf(x1.y, y1.y, b2);
    a = fmaf(x0.z, y0.z, a); b2 = fmaf(x1.z, y1.z, b2);
    a = fmaf(x0.w, y0.w, a); b2 = fmaf(x1.w, y1.w, b2);
    return a + b2;
}

// ---------------- transpose: X[8192][512] -> XT[512][8192], 64x64 tiles ----------------
__global__ __launch_bounds__(256)
void transpose_kernel(const float* __restrict__ X, float* __restrict__ XT)
{
    __shared__ float tile[64][65];
    const int t  = threadIdx.x;
    const int tx = t & 15;
    const int ty = t >> 4;
    const int bm = blockIdx.x * 64;   // row block in X
    const int bn = blockIdx.y * 64;   // col block in X
#pragma unroll
    for (int i = 0; i < 4; ++i) {
        const int r = ty + i * 16;
        const float4 v = *(const float4*)(X + (size_t)(bm + r) * 512 + bn + tx * 4);
        tile[r][tx * 4 + 0] = v.x; tile[r][tx * 4 + 1] = v.y;
        tile[r][tx * 4 + 2] = v.z; tile[r][tx * 4 + 3] = v.w;
    }
    __syncthreads();
#pragma unroll
    for (int i = 0; i < 4; ++i) {
        const int r = ty + i * 16;    // XT row = bn + r
        float4 v;
        v.x = tile[tx * 4 + 0][r];
        v.y = tile[tx * 4 + 1][r];
        v.z = tile[tx * 4 + 2][r];
        v.w = tile[tx * 4 + 3][r];
        *(float4*)(XT + (size_t)(bn + r) * CROWS + bm + tx * 4) = v;
    }
}

// -------- fused QKV TN GEMM: [8192,1536] = XT^T @ [Wq|Wk|Wv], 128x128 tiles --------
// grid (64, 12) = 768 blocks = 3 blocks/CU; 8x8 micro-tile (DS/VALU balanced);
// 32 KB LDS/block keeps 3-block residency (R5-proven, 172 us). Unchanged this round.
__global__ __launch_bounds__(256)
void gemm_qkv(const float* __restrict__ AT,
              const float* __restrict__ Wq, const float* __restrict__ Wk,
              const float* __restrict__ Wv,
              float* __restrict__ Qp, float* __restrict__ Kp, float* __restrict__ Vd)
{
    __shared__ __align__(16) float As[2][16][128];
    __shared__ __align__(16) float Bs[2][16][128];
    const int t  = threadIdx.x;
    const int tx = t & 15;
    const int ty = t >> 4;
    const int bm  = blockIdx.x * 128;
    const int grp = blockIdx.y >> 2;           // 0=Q, 1=K, 2=V
    const int bn  = (blockIdx.y & 3) * 128;
    const float* B = (grp == 0) ? Wq : (grp == 1) ? Wk : Wv;

    float acc[8][8];
#pragma unroll
    for (int i = 0; i < 8; ++i)
#pragma unroll
        for (int j = 0; j < 8; ++j) acc[i][j] = 0.f;

    auto stage = [&](int buf, int kt) {
        const int k0 = kt * 16;
#pragma unroll
        for (int i = 0; i < 2; ++i) {        // 512 float4 each for A and B tiles
            const int L = t + i * 256;
            const int k = L >> 5, c4 = L & 31;
            async16(AT + (size_t)(k0 + k) * CROWS + bm + c4 * 4,
                    &As[buf][0][0] + L * 4);
            async16(B + (size_t)(k0 + k) * 512 + bn + c4 * 4,
                    &Bs[buf][0][0] + L * 4);
        }
    };

    stage(0, 0);
    for (int kt = 0; kt < 32; ++kt) {
        const int buf = kt & 1;
        __syncthreads();                 // vmcnt drain: buf's staged loads landed
        if (kt + 1 < 32) stage(buf ^ 1, kt + 1);
#pragma unroll
        for (int k = 0; k < 16; ++k) {
            float af[8], bf[8];
            *(float4*)&af[0] = *(const float4*)&As[buf][k][ty * 8];
            *(float4*)&af[4] = *(const float4*)&As[buf][k][ty * 8 + 4];
            *(float4*)&bf[0] = *(const float4*)&Bs[buf][k][tx * 4];
            *(float4*)&bf[4] = *(const float4*)&Bs[buf][k][64 + tx * 4];
#pragma unroll
            for (int i = 0; i < 8; ++i)
#pragma unroll
                for (int j = 0; j < 8; ++j)
                    acc[i][j] = fmaf(af[i], bf[j], acc[i][j]);
        }
    }

    if (grp < 2) {
        // fused dpfp per head-half. Head cols on 16 tx-lanes x 4;
        // roll = one intra-16-lane shuffle; L1 norm = rowsum16 across tx.
        float* dst = grp ? Kp : Qp;
        const int ln  = t & 63;
        const int lnp = (ln & 48) | ((ln + 15) & 15);   // same ty-row, tx-1 (mod 16)
        const int hA  = bn >> 6;
#pragma unroll
        for (int hh = 0; hh < 2; ++hh) {
            const int h = hA + hh;
#pragma unroll
            for (int i = 0; i < 8; ++i) {
                const int m = bm + ty * 8 + i;
                float ap[4], an[4];
#pragma unroll
                for (int j = 0; j < 4; ++j) {
                    const float v = acc[i][hh * 4 + j];
                    ap[j] = fmaxf(v, 0.f);
                    an[j] = fmaxf(-v, 0.f);
                }
                const float sap = __shfl(ap[3], lnp);
                const float san = __shfl(an[3], lnp);
                const float p0  = (tx == 0) ? san : sap;    // col0 wraps to an[63]
                const float p64 = (tx == 0) ? sap : san;    // col64 wraps to ap[63]
                float y0[4], y1[4];
                y0[0] = ap[0] * p0;    y1[0] = an[0] * p64;
                y0[1] = ap[1] * ap[0]; y1[1] = an[1] * an[0];
                y0[2] = ap[2] * ap[1]; y1[2] = an[2] * an[1];
                y0[3] = ap[3] * ap[2]; y1[3] = an[3] * an[2];
                float s = (y0[0] + y0[1] + y0[2] + y0[3]) + (y1[0] + y1[1] + y1[2] + y1[3]);
                s = rowsum16(s);
                const float inv = 1.f / (s + 1e-6f);
                float4 o0, o1;
                o0.x = y0[0] * inv; o0.y = y0[1] * inv; o0.z = y0[2] * inv; o0.w = y0[3] * inv;
                o1.x = y1[0] * inv; o1.y = y1[1] * inv; o1.z = y1[2] * inv; o1.w = y1[3] * inv;
                *(float4*)(dst + (size_t)m * 1024 + h * 128 + tx * 4)      = o0;
                *(float4*)(dst + (size_t)m * 1024 + h * 128 + 64 + tx * 4) = o1;
            }
        }
    } else {
#pragma unroll
        for (int i = 0; i < 8; ++i) {
            const int m = bm + ty * 8 + i;
            float4 o0, o1;
            o0.x = acc[i][0]; o0.y = acc[i][1]; o0.z = acc[i][2]; o0.w = acc[i][3];
            o1.x = acc[i][4]; o1.y = acc[i][5]; o1.z = acc[i][6]; o1.w = acc[i][7];
            *(float4*)(Vd + (size_t)m * 512 + bn + tx * 4)      = o0;
            *(float4*)(Vd + (size_t)m * 512 + bn + 64 + tx * 4) = o1;
        }
    }
}

// ---------------- TN GEMM for Wo: C[8192][512] = outsT^T @ Wo + bo ----------------
// R6 change: BK=32 (16 barriers instead of 32; LDS 48 KB, still 2 blocks/CU at
// grid 512) — halves the per-K-tile barrier-drain exposure.
__global__ __launch_bounds__(256)
void gemm_wo(const float* __restrict__ AT, const float* __restrict__ B,
             const float* __restrict__ bias, float* __restrict__ C)
{
    __shared__ __align__(16) float As[2][32][128];
    __shared__ __align__(16) float Bs[2][32][64];
    const int t  = threadIdx.x;
    const int tx = t & 15;
    const int ty = t >> 4;
    const int bm = blockIdx.x * 128;
    const int bn = blockIdx.y * 64;

    float acc[8][4];
#pragma unroll
    for (int i = 0; i < 8; ++i)
#pragma unroll
        for (int j = 0; j < 4; ++j) acc[i][j] = 0.f;

    auto stage = [&](int buf, int kt) {
        const int k0 = kt * 32;
        // A tile: 32 k-rows x 128 m = 1024 float4
#pragma unroll
        for (int i = 0; i < 4; ++i) {
            const int L = t + i * 256;
            const int k = L >> 5, c4 = L & 31;
            async16(AT + (size_t)(k0 + k) * CROWS + bm + c4 * 4,
                    &As[buf][0][0] + L * 4);
        }
        // B tile: 32 k-rows x 64 n = 512 float4
#pragma unroll
        for (int i = 0; i < 2; ++i) {
            const int L = t + i * 256;
            const int k = L >> 4, c4 = L & 15;
            async16(B + (size_t)(k0 + k) * 512 + bn + c4 * 4,
                    &Bs[buf][0][0] + L * 4);
        }
    };

    stage(0, 0);
    for (int kt = 0; kt < 16; ++kt) {
        const int buf = kt & 1;
        __syncthreads();
        if (kt + 1 < 16) stage(buf ^ 1, kt + 1);
#pragma unroll
        for (int k = 0; k < 32; ++k) {
            float af[8], bf[4];
            *(float4*)&af[0] = *(const float4*)&As[buf][k][ty * 8];
            *(float4*)&af[4] = *(const float4*)&As[buf][k][ty * 8 + 4];
            *(float4*)&bf[0] = *(const float4*)&Bs[buf][k][tx * 4];
#pragma unroll
            for (int i = 0; i < 8; ++i)
#pragma unroll
                for (int j = 0; j < 4; ++j)
                    acc[i][j] = fmaf(af[i], bf[j], acc[i][j]);
        }
    }

#pragma unroll
    for (int i = 0; i < 8; ++i) {
        const int m = bm + ty * 8 + i;
        float4 o;
        o.x = acc[i][0]; o.y = acc[i][1]; o.z = acc[i][2]; o.w = acc[i][3];
        const float4 bb = *(const float4*)(bias + bn + tx * 4);
        o.x += bb.x; o.y += bb.y; o.z += bb.z; o.w += bb.w;
        *(float4*)(C + (size_t)m * 512 + bn + tx * 4) = o;
    }
}

// ---------------- gate: beta = sigmoid(x @ Wg), [32768, 8], whole sequence ----------------
__global__ __launch_bounds__(256)
void gemm_g_kernel(const float* __restrict__ X, const float* __restrict__ Wg,
                   float* __restrict__ Bt)
{
    const int idx = blockIdx.x * 256 + threadIdx.x;   // 262144 total
    const int row = idx >> 3;
    const int c   = idx & 7;
    const float4* x4 = (const float4*)(X + (size_t)row * DMODEL);
    float acc = 0.f;
    for (int k4 = 0; k4 < 128; ++k4) {
        const float4 xv = x4[k4];
        acc = fmaf(xv.x, Wg[(k4 * 4 + 0) * 8 + c], acc);
        acc = fmaf(xv.y, Wg[(k4 * 4 + 1) * 8 + c], acc);
        acc = fmaf(xv.z, Wg[(k4 * 4 + 2) * 8 + c], acc);
        acc = fmaf(xv.w, Wg[(k4 * 4 + 3) * 8 + c], acc);
    }
    Bt[idx] = 1.f / (1.f + expf(-acc));
}

// ---------------- scan (16 rows x 16 col-lanes, 256 blocks) ----------------
// R6 change: register-prefetch ring deepened 4 -> 8 slots, distance 2 -> 4 steps
// (~528 issue-cycles of slack vs ~120-cyc DS latency; VGPRs are free — occupancy
// is structurally grid-capped at 1 wave/SIMD). Slot = s&7 stays consistent across
// superblocks (SB%8==0); fp (prev-step k) at (s+7)&7, disjoint from write slot
// (s+4)&7. 2-step look-ahead linearization + packed sd kept.
__global__ __launch_bounds__(256)
void scan_kernel(const float* __restrict__ Qp, const float* __restrict__ Kp,
                 const float* __restrict__ Vd, const float* __restrict__ Bt,
                 float* __restrict__ outsT, float* __restrict__ Wst,
                 int s0, int first)
{
    const int blk = blockIdx.x;
    const int bh  = blk & 63;
    const int rg  = blk >> 6;
    const int b   = bh >> 3;
    const int h   = bh & 7;
    const int t   = threadIdx.x;
    const int c      = t & 15;     // col lane
    const int rloc   = t >> 4;     // row within group of 16
    const int wv  = t >> 6;        // wave id 0..3
    const int ln  = t & 63;        // lane within wave

    __shared__ __align__(16) float sk[2][SB][PHI];
    __shared__ __align__(16) float sq[2][SB][PHI];
    __shared__ __align__(16) float sv[2][SB][16];
    __shared__ __align__(16) float sb2[2][SB];
    __shared__ __align__(16) float sd[2][SB][4];   // {kk, kq1, kq0, beta}

    const size_t bh128 = (size_t)(b * 8 + h) * 128;

    float w[8];
    float* wslot = Wst + (size_t)blk * 2048 + t * 8;
    if (first) {
#pragma unroll
        for (int j = 0; j < 8; ++j) w[j] = 0.f;
    } else {
        const float4 w0 = *(const float4*)(wslot);
        const float4 w1 = *(const float4*)(wslot + 4);
        w[0] = w0.x; w[1] = w0.y; w[2] = w0.z; w[3] = w0.w;
        w[4] = w1.x; w[5] = w1.y; w[6] = w1.z; w[7] = w1.w;
    }

    auto stage = [&](int sbuf, int sb) {
        const int sqb = sb * SB;
        if (wv < 2) {
#pragma unroll
            for (int i = 0; i < 8; ++i) {
                const int L  = i * 128 + wv * 64 + ln;
                const int sl = L >> 5, c4 = L & 31;
                async16(Kp + (size_t)(sqb + sl) * 8192 + bh128 + c4 * 4,
                        &sk[sbuf][0][0] + L * 4);
            }
            {
                const int L  = wv * 64 + ln;
                const int sl = L >> 2, c4 = L & 3;
                async16(Vd + (size_t)(sqb + sl) * 4096 + b * 512 + h * 64 + rg * 16 + c4 * 4,
                        &sv[sbuf][0][0] + L * 4);
            }
        } else {
#pragma unroll
            for (int i = 0; i < 8; ++i) {
                const int L  = i * 128 + (wv - 2) * 64 + ln;
                const int sl = L >> 5, c4 = L & 31;
                async16(Qp + (size_t)(sqb + sl) * 8192 + bh128 + c4 * 4,
                        &sq[sbuf][0][0] + L * 4);
            }
            if (wv == 2 && ln < SB) {
                async4(Bt + (size_t)(s0 + sqb + ln) * 64 + b * 8 + h,
                       &sb2[sbuf][0] + ln);
            }
        }
    };

    auto dots_phase = [&](int buf, int sb) {
        const int sl0 = 2 * rloc;
        const float* kmp = (rloc == 0) ? &sk[buf ^ 1][SB - 1][0] : &sk[buf][sl0 - 1][0];
        const float4 km0 = *(const float4*)(kmp + 4 * c);
        const float4 km1 = *(const float4*)(kmp + 64 + 4 * c);
        const float4 ka0 = *(const float4*)&sk[buf][sl0][4 * c];
        const float4 ka1 = *(const float4*)&sk[buf][sl0][64 + 4 * c];
        const float4 kb0 = *(const float4*)&sk[buf][sl0 + 1][4 * c];
        const float4 kb1 = *(const float4*)&sk[buf][sl0 + 1][64 + 4 * c];
        const float4 qa0 = *(const float4*)&sq[buf][sl0][4 * c];
        const float4 qa1 = *(const float4*)&sq[buf][sl0][64 + 4 * c];
        const float4 qb0 = *(const float4*)&sq[buf][sl0 + 1][4 * c];
        const float4 qb1 = *(const float4*)&sq[buf][sl0 + 1][64 + 4 * c];
        const float kk_a  = rowsum16(dot8(km0, km1, ka0, ka1));
        const float kq1_a = rowsum16(dot8(km0, km1, qa0, qa1));
        const float kq0_a = rowsum16(dot8(ka0, ka1, qa0, qa1));
        const float kk_b  = rowsum16(dot8(ka0, ka1, kb0, kb1));
        const float kq1_b = rowsum16(dot8(ka0, ka1, qb0, qb1));
        const float kq0_b = rowsum16(dot8(kb0, kb1, qb0, qb1));
        if (c == 0) {
            const bool z = (sb == 0) && (rloc == 0);   // chunk's step 0: d_prev == 0
            sd[buf][sl0][0] = z ? 0.f : kk_a;
            sd[buf][sl0][1] = z ? 0.f : kq1_a;
            sd[buf][sl0][2] = kq0_a;
            sd[buf][sl0][3] = sb2[buf][sl0];
            sd[buf][sl0 + 1][0] = kk_b;
            sd[buf][sl0 + 1][1] = kq1_b;
            sd[buf][sl0 + 1][2] = kq0_b;
            sd[buf][sl0 + 1][3] = sb2[buf][sl0 + 1];
        }
    };

    struct Frag { float4 k0, k1, q0, q1; float bb, bv, kk, kq1, kq0; };
    Frag r[8];
    float d_prev = 0.f;

    auto preload = [&](Frag& f, int sbuf, int sl) {
        f.k0 = *(const float4*)&sk[sbuf][sl][4 * c];
        f.k1 = *(const float4*)&sk[sbuf][sl][64 + 4 * c];
        f.q0 = *(const float4*)&sq[sbuf][sl][4 * c];
        f.q1 = *(const float4*)&sq[sbuf][sl][64 + 4 * c];
        const float4 dd = *(const float4*)&sd[sbuf][sl][0];
        f.kk = dd.x; f.kq1 = dd.y; f.kq0 = dd.z; f.bb = dd.w;
        f.bv = f.bb * sv[sbuf][sl][rloc];
    };

    auto step_compute = [&](const Frag& f, const Frag& fp, int g) {
        float A0 = w[0] * f.k0.x;
        float A1 = w[4] * f.k1.x;
        A0 = fmaf(w[1], f.k0.y, A0); A1 = fmaf(w[5], f.k1.y, A1);
        A0 = fmaf(w[2], f.k0.z, A0); A1 = fmaf(w[6], f.k1.z, A1);
        A0 = fmaf(w[3], f.k0.w, A0); A1 = fmaf(w[7], f.k1.w, A1);
        float Q0 = w[0] * f.q0.x;
        float Q1 = w[4] * f.q1.x;
        Q0 = fmaf(w[1], f.q0.y, Q0); Q1 = fmaf(w[5], f.q1.y, Q1);
        Q0 = fmaf(w[2], f.q0.z, Q0); Q1 = fmaf(w[6], f.q1.z, Q1);
        Q0 = fmaf(w[3], f.q0.w, Q0); Q1 = fmaf(w[7], f.q1.w, Q1);
        const float Ar  = rowsum16(A0 + A1);
        const float Aqr = rowsum16(Q0 + Q1);
        w[0] = fmaf(d_prev, fp.k0.x, w[0]);
        w[1] = fmaf(d_prev, fp.k0.y, w[1]);
        w[2] = fmaf(d_prev, fp.k0.z, w[2]);
        w[3] = fmaf(d_prev, fp.k0.w, w[3]);
        w[4] = fmaf(d_prev, fp.k1.x, w[4]);
        w[5] = fmaf(d_prev, fp.k1.y, w[5]);
        w[6] = fmaf(d_prev, fp.k1.z, w[6]);
        w[7] = fmaf(d_prev, fp.k1.w, w[7]);
        const float a = fmaf(d_prev, f.kk, Ar);
        const float d = fmaf(-f.bb, a, f.bv);
        float o = fmaf(d_prev, f.kq1, Aqr);
        o = fmaf(d, f.kq0, o);
        if (c == 0)
            outsT[(size_t)(h * DK + rg * 16 + rloc) * CROWS + g * BATCH + b] = o;
        d_prev = d;
    };

    // frag-(-1) k must be 0 (multiplied by d_prev=0; avoid NaN from stale regs).
    // Step -1 maps to ring slot 7.
    r[7].k0 = make_float4(0.f, 0.f, 0.f, 0.f);
    r[7].k1 = make_float4(0.f, 0.f, 0.f, 0.f);

    stage(0, 0);
    for (int sb = 0; sb < NSB; ++sb) {
        const int buf = sb & 1;
        __syncthreads();                     // staged loads for buf complete
        dots_phase(buf, sb);
        __syncthreads();                     // sd visible; prev-buffer boundary reads done
        if (sb + 1 < NSB) stage(buf ^ 1, sb + 1);
        preload(r[0], buf, 0);               // steps 0..3: slots 0..3 (boundary refill)
        preload(r[1], buf, 1);
        preload(r[2], buf, 2);
        preload(r[3], buf, 3);
#pragma unroll
        for (int s = 0; s < SB; ++s) {
            if (s + 4 < SB) preload(r[(s + 4) & 7], buf, s + 4);   // distance-4 prefetch
            step_compute(r[s & 7], r[(s + 7) & 7], sb * SB + s);
        }
    }

    // apply the pending final update (step 1023 -> ring slot 1023&7 == 7)
    w[0] = fmaf(d_prev, r[7].k0.x, w[0]);
    w[1] = fmaf(d_prev, r[7].k0.y, w[1]);
    w[2] = fmaf(d_prev, r[7].k0.z, w[2]);
    w[3] = fmaf(d_prev, r[7].k0.w, w[3]);
    w[4] = fmaf(d_prev, r[7].k1.x, w[4]);
    w[5] = fmaf(d_prev, r[7].k1.y, w[5]);
    w[6] = fmaf(d_prev, r[7].k1.z, w[6]);
    w[7] = fmaf(d_prev, r[7].k1.w, w[7]);

    float4 w0, w1;
    w0.x = w[0]; w0.y = w[1]; w0.z = w[2]; w0.w = w[3];
    w1.x = w[4]; w1.y = w[5]; w1.z = w[6]; w1.w = w[7];
    *(float4*)(wslot)     = w0;
    *(float4*)(wslot + 4) = w1;
}

extern "C" void kernel_launch(void* const* d_in, const int* in_sizes, int n_in,
                              void* d_out, int out_size, void* d_ws, size_t ws_size,
                              hipStream_t stream)
{
    const float* x  = (const float*)d_in[0];
    const float* Wq = (const float*)d_in[1];
    const float* Wk = (const float*)d_in[2];
    const float* Wv = (const float*)d_in[3];
    const float* Wg = (const float*)d_in[4];
    const float* Wo = (const float*)d_in[5];
    const float* bo = (const float*)d_in[6];
    float* out = (float*)d_out;

    // workspace (floats), ~99 MB. XTc (x^T per chunk) ALIASES tmp (scan outsT):
    // per chunk: transpose->XTc | QKV GEMM reads XTc | scan writes tmp | Wo GEMM
    // reads tmp | next chunk's transpose overwrites — stream-ordered, no overlap.
    float* ws  = (float*)d_ws;
    float* XTc = ws;                                   // [512][8192]  (= tmp)
    float* tmp = ws;                                   // [512][8192]  (scan outsT)
    float* Qp  = ws  + (size_t)512 * CROWS;            // [8192][1024]
    float* Kp  = Qp  + (size_t)CROWS * 1024;           // [8192][1024]
    float* Vd  = Kp  + (size_t)CROWS * 1024;           // [8192][512]
    float* Bt  = Vd  + (size_t)CROWS * 512;            // [32768][8]
    float* Wst = Bt  + (size_t)(SEQ * BATCH) * 8;      // [256][2048]
    (void)in_sizes; (void)n_in; (void)out_size; (void)ws_size;

    const dim3 gt(CROWS / 64, DMODEL / 64);    // (128, 8) transpose grid
    const dim3 gq(CROWS / 128, 12);            // (64, 12) = 768 blocks fused QKV
    const dim3 go(CROWS / 128, DMODEL / 64);   // (64, 8)  = 512 blocks Wo
    const int NCH = SEQ / CHUNK;               // 4

    gemm_g_kernel<<<(SEQ * BATCH * 8) / 256, 256, 0, stream>>>(x, Wg, Bt);

    for (int c = 0; c < NCH; ++c) {
        const float* xc = x + (size_t)c * CROWS * DMODEL;
        transpose_kernel<<<gt, 256, 0, stream>>>(xc, XTc);
        gemm_qkv<<<gq, 256, 0, stream>>>(XTc, Wq, Wk, Wv, Qp, Kp, Vd);
        scan_kernel<<<256, 256, 0, stream>>>(Qp, Kp, Vd, Bt, tmp, Wst,
                                             c * CHUNK, c == 0 ? 1 : 0);
        gemm_wo<<<go, 256, 0, stream>>>(tmp, Wo, bo,
                                        out + (size_t)c * CROWS * DMODEL);
    }
}

// Round 7
// 1324.030 us; speedup vs baseline: 1.5882x; 1.2195x over previous
//
#include <hip/hip_runtime.h>

#define SEQ 4096
#define BATCH 8
#define HEADS 8
#define DMODEL 512
#define DK 64
#define PHI 128
#define CHUNK 1024
#define CROWS (CHUNK * BATCH)          // 8192 rows per chunk
#define SB 32                          // scan superblock (steps staged per barrier)
#define NSB (CHUNK / SB)               // 32

typedef float f32x4 __attribute__((ext_vector_type(4)));
typedef short s16x8 __attribute__((ext_vector_type(8)));

__device__ __forceinline__ void async16(const float* g, float* l)
{
    __builtin_amdgcn_global_load_lds((const __attribute__((address_space(1))) void*)g,
                                     (__attribute__((address_space(3))) void*)l, 16, 0, 0);
}
__device__ __forceinline__ void async4(const float* g, float* l)
{
    __builtin_amdgcn_global_load_lds((const __attribute__((address_space(1))) void*)g,
                                     (__attribute__((address_space(3))) void*)l, 4, 0, 0);
}

__device__ __forceinline__ float rowsum16(float x)
{
    x += __int_as_float(__builtin_amdgcn_update_dpp(0, __float_as_int(x), 0x121, 0xF, 0xF, true)); // row_ror:1
    x += __int_as_float(__builtin_amdgcn_update_dpp(0, __float_as_int(x), 0x122, 0xF, 0xF, true)); // row_ror:2
    x += __int_as_float(__builtin_amdgcn_update_dpp(0, __float_as_int(x), 0x124, 0xF, 0xF, true)); // row_ror:4
    x += __int_as_float(__builtin_amdgcn_update_dpp(0, __float_as_int(x), 0x128, 0xF, 0xF, true)); // row_ror:8
    return x;
}

__device__ __forceinline__ float dot8(const float4 x0, const float4 x1,
                                      const float4 y0, const float4 y1)
{
    float a  = x0.x * y0.x;
    float b2 = x1.x * y1.x;
    a = fmaf(x0.y, y0.y, a); b2 = fmaf(x1.y, y1.y, b2);
    a = fmaf(x0.z, y0.z, a); b2 = fmaf(x1.z, y1.z, b2);
    a = fmaf(x0.w, y0.w, a); b2 = fmaf(x1.w, y1.w, b2);
    return a + b2;
}

// pack two fp32's top halves (truncate-to-bf16) into one u32: low16=bf16(a), high16=bf16(b)
__device__ __forceinline__ unsigned packhi2(unsigned a, unsigned b)
{
    return (b & 0xFFFF0000u) | (a >> 16);
}

// -------- fused QKV MFMA GEMM: [8192,1536] = x[8192,512] @ [Wq|Wk|Wv] --------
// Split-bf16 (x = hi + lo, truncated): 3 MFMAs per tile (hh + hl + lh); dropped
// lo*lo term ~2^-16 relative — fp32-grade accuracy. The fp32-VALU version was
// LDS-BW-bound (~3072 DS cyc vs 2048 VALU per block-kt); bf16 operands + matrix
// pipe cut DS bytes ~3x and move FMAs off the VALU.
// Block 128m x 128n, 4 waves (2x2), wave = 64x64 = 4x4 MFMA tiles, BK=32 (16 barriers).
// A: reg-staged -> packed bf16 hi/lo LDS [128][40] (pad 40 => conflict-free b128 frags).
// B: reg-staged f32 LDS [32][132] (pad => 2-way b32 reads), split in-reg per n-frag.
// No x-transpose needed (MFMA A-operand reads row-major x) — transpose kernel deleted.
// C/D layout (HW-verified m89): col = lane&15, row = (lane>>4)*4 + j.
// blockIdx.y: 0-3 -> Q (dpfp epilogue), 4-7 -> K (dpfp), 8-11 -> V (plain store).
__global__ __launch_bounds__(256)
void gemm_qkv_mfma(const float* __restrict__ x,
                   const float* __restrict__ Wq, const float* __restrict__ Wk,
                   const float* __restrict__ Wv,
                   float* __restrict__ Qp, float* __restrict__ Kp, float* __restrict__ Vd)
{
    __shared__ __align__(16) unsigned short Ah[2][128][40];   // 20 KB
    __shared__ __align__(16) unsigned short Al[2][128][40];   // 20 KB
    __shared__ __align__(16) float          Bs[2][32][132];   // 33 KB

    const int t    = threadIdx.x;
    const int l    = t & 63;
    const int wv   = t >> 6;           // wave 0..3
    const int wm   = wv >> 1;          // wave m-half 0..1
    const int wn   = wv & 1;           // wave n-half 0..1
    const int tx16 = l & 15;
    const int g4   = l >> 4;           // 0..3
    const int bm   = blockIdx.x * 128;
    const int grp  = blockIdx.y >> 2;  // 0=Q, 1=K, 2=V
    const int bn   = (blockIdx.y & 3) * 128;
    const float* W = (grp == 0) ? Wq : (grp == 1) ? Wk : Wv;

    f32x4 acc[4][4];
#pragma unroll
    for (int i = 0; i < 4; ++i)
#pragma unroll
        for (int j = 0; j < 4; ++j) acc[i][j] = 0.f;

    float4 xr[4], wr[4];

    auto loadA = [&](int kt) {           // x tile 128 x 32, coalesced (8 lanes = 128B)
#pragma unroll
        for (int i = 0; i < 4; ++i) {
            const int L = t + i * 256;
            const int row = L >> 3, kq = (L & 7) << 2;
            xr[i] = *(const float4*)(x + (size_t)(bm + row) * 512 + kt * 32 + kq);
        }
    };
    auto writeA = [&](int buf) {         // split + pack -> bf16 hi/lo LDS
#pragma unroll
        for (int i = 0; i < 4; ++i) {
            const int L = t + i * 256;
            const int row = L >> 3, kq = (L & 7) << 2;
            const float4 v = xr[i];
            const unsigned u0 = __float_as_uint(v.x), u1 = __float_as_uint(v.y);
            const unsigned u2 = __float_as_uint(v.z), u3 = __float_as_uint(v.w);
            const float l0 = v.x - __uint_as_float(u0 & 0xFFFF0000u);
            const float l1 = v.y - __uint_as_float(u1 & 0xFFFF0000u);
            const float l2 = v.z - __uint_as_float(u2 & 0xFFFF0000u);
            const float l3 = v.w - __uint_as_float(u3 & 0xFFFF0000u);
            *(uint2*)&Ah[buf][row][kq] =
                make_uint2(packhi2(u0, u1), packhi2(u2, u3));
            *(uint2*)&Al[buf][row][kq] =
                make_uint2(packhi2(__float_as_uint(l0), __float_as_uint(l1)),
                           packhi2(__float_as_uint(l2), __float_as_uint(l3)));
        }
    };
    auto loadB = [&](int kt) {           // W tile 32 x 128, coalesced
#pragma unroll
        for (int i = 0; i < 4; ++i) {
            const int L = t + i * 256;
            const int k = L >> 5, c4 = (L & 31) << 2;
            wr[i] = *(const float4*)(W + (size_t)(kt * 32 + k) * 512 + bn + c4);
        }
    };
    auto writeB = [&](int buf) {
#pragma unroll
        for (int i = 0; i < 4; ++i) {
            const int L = t + i * 256;
            const int k = L >> 5, c4 = (L & 31) << 2;
            *(float4*)&Bs[buf][k][c4] = wr[i];
        }
    };

    auto compute = [&](int buf) {
        s16x8 ah[4], al[4];
#pragma unroll
        for (int mf = 0; mf < 4; ++mf) {
            const int rowA = wm * 64 + mf * 16 + tx16;
            ah[mf] = *(const s16x8*)&Ah[buf][rowA][g4 * 8];
            al[mf] = *(const s16x8*)&Al[buf][rowA][g4 * 8];
        }
#pragma unroll
        for (int nf = 0; nf < 4; ++nf) {
            const int ncol = wn * 64 + nf * 16 + tx16;
            float bv[8];
#pragma unroll
            for (int i = 0; i < 8; ++i) bv[i] = Bs[buf][g4 * 8 + i][ncol];
            unsigned uh[4], ul[4];
#pragma unroll
            for (int w2 = 0; w2 < 4; ++w2) {
                const unsigned ua = __float_as_uint(bv[2 * w2]);
                const unsigned ub = __float_as_uint(bv[2 * w2 + 1]);
                const float la = bv[2 * w2]     - __uint_as_float(ua & 0xFFFF0000u);
                const float lb = bv[2 * w2 + 1] - __uint_as_float(ub & 0xFFFF0000u);
                uh[w2] = packhi2(ua, ub);
                ul[w2] = packhi2(__float_as_uint(la), __float_as_uint(lb));
            }
            int4 bhv = make_int4(uh[0], uh[1], uh[2], uh[3]);
            int4 blv = make_int4(ul[0], ul[1], ul[2], ul[3]);
            const s16x8 bh = *(const s16x8*)&bhv;
            const s16x8 bl = *(const s16x8*)&blv;
#pragma unroll
            for (int mf = 0; mf < 4; ++mf) {
                acc[mf][nf] = __builtin_amdgcn_mfma_f32_16x16x32_bf16(ah[mf], bh, acc[mf][nf], 0, 0, 0);
                acc[mf][nf] = __builtin_amdgcn_mfma_f32_16x16x32_bf16(ah[mf], bl, acc[mf][nf], 0, 0, 0);
                acc[mf][nf] = __builtin_amdgcn_mfma_f32_16x16x32_bf16(al[mf], bh, acc[mf][nf], 0, 0, 0);
            }
        }
    };

    loadA(0); loadB(0); writeA(0); writeB(0);
    for (int kt = 0; kt < 16; ++kt) {
        const int buf = kt & 1;
        __syncthreads();                 // publishes buf's A(bf16)/B(f32) tiles
        if (kt < 15) { loadA(kt + 1); loadB(kt + 1); }
        compute(buf);
        if (kt < 15) { writeA(buf ^ 1); writeB(buf ^ 1); }
    }

    if (grp < 2) {
        // fused dpfp in MFMA C-layout. This wave's 64 n-cols = exactly one head.
        // Lane holds col c = nf*16 + tx16 for rows (g4)*4 + j (+ mf*16 + wm*64).
        // roll (col-1): value of lane-1 within the 16-lane row group; col 0 of the
        // 128-feature vector wraps to an[63], col 64 (an-part start) wraps to ap[63].
        float* dst = grp ? Kp : Qp;
        const int h = (blockIdx.y & 3) * 2 + wn;
        const int prevl = (l & 48) | ((l + 15) & 15);   // lane-1 within 16-lane row
#pragma unroll
        for (int mf = 0; mf < 4; ++mf) {
#pragma unroll
            for (int j = 0; j < 4; ++j) {
                float ap[4], an[4], sap[4], san[4];
#pragma unroll
                for (int nf = 0; nf < 4; ++nf) {
                    const float v = acc[mf][nf][j];
                    ap[nf] = fmaxf(v, 0.f);
                    an[nf] = fmaxf(-v, 0.f);
                }
#pragma unroll
                for (int nf = 0; nf < 4; ++nf) {
                    sap[nf] = __shfl(ap[nf], prevl);
                    san[nf] = __shfl(an[nf], prevl);
                }
                float y0[4], y1[4];
#pragma unroll
                for (int nf = 0; nf < 4; ++nf) {
                    const float pa = (tx16 == 0) ? (nf ? sap[nf - 1] : san[3]) : sap[nf];
                    const float pn = (tx16 == 0) ? (nf ? san[nf - 1] : sap[3]) : san[nf];
                    y0[nf] = ap[nf] * pa;
                    y1[nf] = an[nf] * pn;
                }
                float s = (y0[0] + y0[1] + y0[2] + y0[3]) + (y1[0] + y1[1] + y1[2] + y1[3]);
                s = rowsum16(s);
                const float inv = 1.f / (s + 1e-6f);
                const int m = bm + wm * 64 + mf * 16 + g4 * 4 + j;
#pragma unroll
                for (int nf = 0; nf < 4; ++nf) {
                    dst[(size_t)m * 1024 + h * 128 + nf * 16 + tx16]      = y0[nf] * inv;
                    dst[(size_t)m * 1024 + h * 128 + 64 + nf * 16 + tx16] = y1[nf] * inv;
                }
            }
        }
    } else {
#pragma unroll
        for (int mf = 0; mf < 4; ++mf) {
#pragma unroll
            for (int j = 0; j < 4; ++j) {
                const int m = bm + wm * 64 + mf * 16 + g4 * 4 + j;
#pragma unroll
                for (int nf = 0; nf < 4; ++nf) {
                    Vd[(size_t)m * 512 + (blockIdx.y & 3) * 128 + wn * 64 + nf * 16 + tx16] =
                        acc[mf][nf][j];
                }
            }
        }
    }
}

// ---------------- TN GEMM for Wo: C[8192][512] = outsT^T @ Wo + bo ----------------
// BK=32 (16 barriers; LDS 48 KB, 2 blocks/CU at grid 512). R6-proven.
__global__ __launch_bounds__(256)
void gemm_wo(const float* __restrict__ AT, const float* __restrict__ B,
             const float* __restrict__ bias, float* __restrict__ C)
{
    __shared__ __align__(16) float As[2][32][128];
    __shared__ __align__(16) float Bs[2][32][64];
    const int t  = threadIdx.x;
    const int tx = t & 15;
    const int ty = t >> 4;
    const int bm = blockIdx.x * 128;
    const int bn = blockIdx.y * 64;

    float acc[8][4];
#pragma unroll
    for (int i = 0; i < 8; ++i)
#pragma unroll
        for (int j = 0; j < 4; ++j) acc[i][j] = 0.f;

    auto stage = [&](int buf, int kt) {
        const int k0 = kt * 32;
#pragma unroll
        for (int i = 0; i < 4; ++i) {
            const int L = t + i * 256;
            const int k = L >> 5, c4 = L & 31;
            async16(AT + (size_t)(k0 + k) * CROWS + bm + c4 * 4,
                    &As[buf][0][0] + L * 4);
        }
#pragma unroll
        for (int i = 0; i < 2; ++i) {
            const int L = t + i * 256;
            const int k = L >> 4, c4 = L & 15;
            async16(B + (size_t)(k0 + k) * 512 + bn + c4 * 4,
                    &Bs[buf][0][0] + L * 4);
        }
    };

    stage(0, 0);
    for (int kt = 0; kt < 16; ++kt) {
        const int buf = kt & 1;
        __syncthreads();
        if (kt + 1 < 16) stage(buf ^ 1, kt + 1);
#pragma unroll
        for (int k = 0; k < 32; ++k) {
            float af[8], bf[4];
            *(float4*)&af[0] = *(const float4*)&As[buf][k][ty * 8];
            *(float4*)&af[4] = *(const float4*)&As[buf][k][ty * 8 + 4];
            *(float4*)&bf[0] = *(const float4*)&Bs[buf][k][tx * 4];
#pragma unroll
            for (int i = 0; i < 8; ++i)
#pragma unroll
                for (int j = 0; j < 4; ++j)
                    acc[i][j] = fmaf(af[i], bf[j], acc[i][j]);
        }
    }

#pragma unroll
    for (int i = 0; i < 8; ++i) {
        const int m = bm + ty * 8 + i;
        float4 o;
        o.x = acc[i][0]; o.y = acc[i][1]; o.z = acc[i][2]; o.w = acc[i][3];
        const float4 bb = *(const float4*)(bias + bn + tx * 4);
        o.x += bb.x; o.y += bb.y; o.z += bb.z; o.w += bb.w;
        *(float4*)(C + (size_t)m * 512 + bn + tx * 4) = o;
    }
}

// ---------------- gate: beta = sigmoid(x @ Wg), [32768, 8], whole sequence ----------------
__global__ __launch_bounds__(256)
void gemm_g_kernel(const float* __restrict__ X, const float* __restrict__ Wg,
                   float* __restrict__ Bt)
{
    const int idx = blockIdx.x * 256 + threadIdx.x;   // 262144 total
    const int row = idx >> 3;
    const int c   = idx & 7;
    const float4* x4 = (const float4*)(X + (size_t)row * DMODEL);
    float acc = 0.f;
    for (int k4 = 0; k4 < 128; ++k4) {
        const float4 xv = x4[k4];
        acc = fmaf(xv.x, Wg[(k4 * 4 + 0) * 8 + c], acc);
        acc = fmaf(xv.y, Wg[(k4 * 4 + 1) * 8 + c], acc);
        acc = fmaf(xv.z, Wg[(k4 * 4 + 2) * 8 + c], acc);
        acc = fmaf(xv.w, Wg[(k4 * 4 + 3) * 8 + c], acc);
    }
    Bt[idx] = 1.f / (1.f + expf(-acc));
}

// ---------------- scan (16 rows x 16 col-lanes, 256 blocks; R6-proven) ----------------
__global__ __launch_bounds__(256)
void scan_kernel(const float* __restrict__ Qp, const float* __restrict__ Kp,
                 const float* __restrict__ Vd, const float* __restrict__ Bt,
                 float* __restrict__ outsT, float* __restrict__ Wst,
                 int s0, int first)
{
    const int blk = blockIdx.x;
    const int bh  = blk & 63;
    const int rg  = blk >> 6;
    const int b   = bh >> 3;
    const int h   = bh & 7;
    const int t   = threadIdx.x;
    const int c      = t & 15;     // col lane
    const int rloc   = t >> 4;     // row within group of 16
    const int wv  = t >> 6;        // wave id 0..3
    const int ln  = t & 63;        // lane within wave

    __shared__ __align__(16) float sk[2][SB][PHI];
    __shared__ __align__(16) float sq[2][SB][PHI];
    __shared__ __align__(16) float sv[2][SB][16];
    __shared__ __align__(16) float sb2[2][SB];
    __shared__ __align__(16) float sd[2][SB][4];   // {kk, kq1, kq0, beta}

    const size_t bh128 = (size_t)(b * 8 + h) * 128;

    float w[8];
    float* wslot = Wst + (size_t)blk * 2048 + t * 8;
    if (first) {
#pragma unroll
        for (int j = 0; j < 8; ++j) w[j] = 0.f;
    } else {
        const float4 w0 = *(const float4*)(wslot);
        const float4 w1 = *(const float4*)(wslot + 4);
        w[0] = w0.x; w[1] = w0.y; w[2] = w0.z; w[3] = w0.w;
        w[4] = w1.x; w[5] = w1.y; w[6] = w1.z; w[7] = w1.w;
    }

    auto stage = [&](int sbuf, int sb) {
        const int sqb = sb * SB;
        if (wv < 2) {
#pragma unroll
            for (int i = 0; i < 8; ++i) {
                const int L  = i * 128 + wv * 64 + ln;
                const int sl = L >> 5, c4 = L & 31;
                async16(Kp + (size_t)(sqb + sl) * 8192 + bh128 + c4 * 4,
                        &sk[sbuf][0][0] + L * 4);
            }
            {
                const int L  = wv * 64 + ln;
                const int sl = L >> 2, c4 = L & 3;
                async16(Vd + (size_t)(sqb + sl) * 4096 + b * 512 + h * 64 + rg * 16 + c4 * 4,
                        &sv[sbuf][0][0] + L * 4);
            }
        } else {
#pragma unroll
            for (int i = 0; i < 8; ++i) {
                const int L  = i * 128 + (wv - 2) * 64 + ln;
                const int sl = L >> 5, c4 = L & 31;
                async16(Qp + (size_t)(sqb + sl) * 8192 + bh128 + c4 * 4,
                        &sq[sbuf][0][0] + L * 4);
            }
            if (wv == 2 && ln < SB) {
                async4(Bt + (size_t)(s0 + sqb + ln) * 64 + b * 8 + h,
                       &sb2[sbuf][0] + ln);
            }
        }
    };

    auto dots_phase = [&](int buf, int sb) {
        const int sl0 = 2 * rloc;
        const float* kmp = (rloc == 0) ? &sk[buf ^ 1][SB - 1][0] : &sk[buf][sl0 - 1][0];
        const float4 km0 = *(const float4*)(kmp + 4 * c);
        const float4 km1 = *(const float4*)(kmp + 64 + 4 * c);
        const float4 ka0 = *(const float4*)&sk[buf][sl0][4 * c];
        const float4 ka1 = *(const float4*)&sk[buf][sl0][64 + 4 * c];
        const float4 kb0 = *(const float4*)&sk[buf][sl0 + 1][4 * c];
        const float4 kb1 = *(const float4*)&sk[buf][sl0 + 1][64 + 4 * c];
        const float4 qa0 = *(const float4*)&sq[buf][sl0][4 * c];
        const float4 qa1 = *(const float4*)&sq[buf][sl0][64 + 4 * c];
        const float4 qb0 = *(const float4*)&sq[buf][sl0 + 1][4 * c];
        const float4 qb1 = *(const float4*)&sq[buf][sl0 + 1][64 + 4 * c];
        const float kk_a  = rowsum16(dot8(km0, km1, ka0, ka1));
        const float kq1_a = rowsum16(dot8(km0, km1, qa0, qa1));
        const float kq0_a = rowsum16(dot8(ka0, ka1, qa0, qa1));
        const float kk_b  = rowsum16(dot8(ka0, ka1, kb0, kb1));
        const float kq1_b = rowsum16(dot8(ka0, ka1, qb0, qb1));
        const float kq0_b = rowsum16(dot8(kb0, kb1, qb0, qb1));
        if (c == 0) {
            const bool z = (sb == 0) && (rloc == 0);   // chunk's step 0: d_prev == 0
            sd[buf][sl0][0] = z ? 0.f : kk_a;
            sd[buf][sl0][1] = z ? 0.f : kq1_a;
            sd[buf][sl0][2] = kq0_a;
            sd[buf][sl0][3] = sb2[buf][sl0];
            sd[buf][sl0 + 1][0] = kk_b;
            sd[buf][sl0 + 1][1] = kq1_b;
            sd[buf][sl0 + 1][2] = kq0_b;
            sd[buf][sl0 + 1][3] = sb2[buf][sl0 + 1];
        }
    };

    struct Frag { float4 k0, k1, q0, q1; float bb, bv, kk, kq1, kq0; };
    Frag r[8];
    float d_prev = 0.f;

    auto preload = [&](Frag& f, int sbuf, int sl) {
        f.k0 = *(const float4*)&sk[sbuf][sl][4 * c];
        f.k1 = *(const float4*)&sk[sbuf][sl][64 + 4 * c];
        f.q0 = *(const float4*)&sq[sbuf][sl][4 * c];
        f.q1 = *(const float4*)&sq[sbuf][sl][64 + 4 * c];
        const float4 dd = *(const float4*)&sd[sbuf][sl][0];
        f.kk = dd.x; f.kq1 = dd.y; f.kq0 = dd.z; f.bb = dd.w;
        f.bv = f.bb * sv[sbuf][sl][rloc];
    };

    auto step_compute = [&](const Frag& f, const Frag& fp, int g) {
        float A0 = w[0] * f.k0.x;
        float A1 = w[4] * f.k1.x;
        A0 = fmaf(w[1], f.k0.y, A0); A1 = fmaf(w[5], f.k1.y, A1);
        A0 = fmaf(w[2], f.k0.z, A0); A1 = fmaf(w[6], f.k1.z, A1);
        A0 = fmaf(w[3], f.k0.w, A0); A1 = fmaf(w[7], f.k1.w, A1);
        float Q0 = w[0] * f.q0.x;
        float Q1 = w[4] * f.q1.x;
        Q0 = fmaf(w[1], f.q0.y, Q0); Q1 = fmaf(w[5], f.q1.y, Q1);
        Q0 = fmaf(w[2], f.q0.z, Q0); Q1 = fmaf(w[6], f.q1.z, Q1);
        Q0 = fmaf(w[3], f.q0.w, Q0); Q1 = fmaf(w[7], f.q1.w, Q1);
        const float Ar  = rowsum16(A0 + A1);
        const float Aqr = rowsum16(Q0 + Q1);
        w[0] = fmaf(d_prev, fp.k0.x, w[0]);
        w[1] = fmaf(d_prev, fp.k0.y, w[1]);
        w[2] = fmaf(d_prev, fp.k0.z, w[2]);
        w[3] = fmaf(d_prev, fp.k0.w, w[3]);
        w[4] = fmaf(d_prev, fp.k1.x, w[4]);
        w[5] = fmaf(d_prev, fp.k1.y, w[5]);
        w[6] = fmaf(d_prev, fp.k1.z, w[6]);
        w[7] = fmaf(d_prev, fp.k1.w, w[7]);
        const float a = fmaf(d_prev, f.kk, Ar);
        const float d = fmaf(-f.bb, a, f.bv);
        float o = fmaf(d_prev, f.kq1, Aqr);
        o = fmaf(d, f.kq0, o);
        if (c == 0)
            outsT[(size_t)(h * DK + rg * 16 + rloc) * CROWS + g * BATCH + b] = o;
        d_prev = d;
    };

    r[7].k0 = make_float4(0.f, 0.f, 0.f, 0.f);
    r[7].k1 = make_float4(0.f, 0.f, 0.f, 0.f);

    stage(0, 0);
    for (int sb = 0; sb < NSB; ++sb) {
        const int buf = sb & 1;
        __syncthreads();                     // staged loads for buf complete
        dots_phase(buf, sb);
        __syncthreads();                     // sd visible; prev-buffer boundary reads done
        if (sb + 1 < NSB) stage(buf ^ 1, sb + 1);
        preload(r[0], buf, 0);
        preload(r[1], buf, 1);
        preload(r[2], buf, 2);
        preload(r[3], buf, 3);
#pragma unroll
        for (int s = 0; s < SB; ++s) {
            if (s + 4 < SB) preload(r[(s + 4) & 7], buf, s + 4);   // distance-4 prefetch
            step_compute(r[s & 7], r[(s + 7) & 7], sb * SB + s);
        }
    }

    // apply the pending final update (step 1023 -> ring slot 7)
    w[0] = fmaf(d_prev, r[7].k0.x, w[0]);
    w[1] = fmaf(d_prev, r[7].k0.y, w[1]);
    w[2] = fmaf(d_prev, r[7].k0.z, w[2]);
    w[3] = fmaf(d_prev, r[7].k0.w, w[3]);
    w[4] = fmaf(d_prev, r[7].k1.x, w[4]);
    w[5] = fmaf(d_prev, r[7].k1.y, w[5]);
    w[6] = fmaf(d_prev, r[7].k1.z, w[6]);
    w[7] = fmaf(d_prev, r[7].k1.w, w[7]);

    float4 w0, w1;
    w0.x = w[0]; w0.y = w[1]; w0.z = w[2]; w0.w = w[3];
    w1.x = w[4]; w1.y = w[5]; w1.z = w[6]; w1.w = w[7];
    *(float4*)(wslot)     = w0;
    *(float4*)(wslot + 4) = w1;
}

extern "C" void kernel_launch(void* const* d_in, const int* in_sizes, int n_in,
                              void* d_out, int out_size, void* d_ws, size_t ws_size,
                              hipStream_t stream)
{
    const float* x  = (const float*)d_in[0];
    const float* Wq = (const float*)d_in[1];
    const float* Wk = (const float*)d_in[2];
    const float* Wv = (const float*)d_in[3];
    const float* Wg = (const float*)d_in[4];
    const float* Wo = (const float*)d_in[5];
    const float* bo = (const float*)d_in[6];
    float* out = (float*)d_out;

    // workspace (floats), ~104 MB (unchanged). tmp = scan outsT [512][8192].
    // Per chunk: QKV-MFMA reads x directly (transpose kernel deleted) | scan writes
    // tmp | Wo GEMM reads tmp — stream-ordered, no overlap.
    float* ws  = (float*)d_ws;
    float* tmp = ws;                                   // [512][8192]  (scan outsT)
    float* Qp  = ws  + (size_t)512 * CROWS;            // [8192][1024]
    float* Kp  = Qp  + (size_t)CROWS * 1024;           // [8192][1024]
    float* Vd  = Kp  + (size_t)CROWS * 1024;           // [8192][512]
    float* Bt  = Vd  + (size_t)CROWS * 512;            // [32768][8]
    float* Wst = Bt  + (size_t)(SEQ * BATCH) * 8;      // [256][2048]
    (void)in_sizes; (void)n_in; (void)out_size; (void)ws_size;

    const dim3 gq(CROWS / 128, 12);            // (64, 12) = 768 blocks fused QKV
    const dim3 go(CROWS / 128, DMODEL / 64);   // (64, 8)  = 512 blocks Wo
    const int NCH = SEQ / CHUNK;               // 4

    gemm_g_kernel<<<(SEQ * BATCH * 8) / 256, 256, 0, stream>>>(x, Wg, Bt);

    for (int c = 0; c < NCH; ++c) {
        const float* xc = x + (size_t)c * CROWS * DMODEL;
        gemm_qkv_mfma<<<gq, 256, 0, stream>>>(xc, Wq, Wk, Wv, Qp, Kp, Vd);
        scan_kernel<<<256, 256, 0, stream>>>(Qp, Kp, Vd, Bt, tmp, Wst,
                                             c * CHUNK, c == 0 ? 1 : 0);
        gemm_wo<<<go, 256, 0, stream>>>(tmp, Wo, bo,
                                        out + (size_t)c * CROWS * DMODEL);
    }
}

// Round 9
// 1307.249 us; speedup vs baseline: 1.6085x; 1.0128x over previous
//
#include <hip/hip_runtime.h>

#define SEQ 4096
#define BATCH 8
#define HEADS 8
#define DMODEL 512
#define DK 64
#define PHI 128
#define CHUNK 1024
#define CROWS (CHUNK * BATCH)          // 8192 rows per chunk
#define SB 32                          // scan superblock (steps staged per barrier)
#define NSB (CHUNK / SB)               // 32

typedef float f32x4 __attribute__((ext_vector_type(4)));
typedef short s16x8 __attribute__((ext_vector_type(8)));

__device__ __forceinline__ void async16(const float* g, float* l)
{
    __builtin_amdgcn_global_load_lds((const __attribute__((address_space(1))) void*)g,
                                     (__attribute__((address_space(3))) void*)l, 16, 0, 0);
}
__device__ __forceinline__ void async4(const float* g, float* l)
{
    __builtin_amdgcn_global_load_lds((const __attribute__((address_space(1))) void*)g,
                                     (__attribute__((address_space(3))) void*)l, 4, 0, 0);
}

__device__ __forceinline__ float rowsum16(float x)
{
    x += __int_as_float(__builtin_amdgcn_update_dpp(0, __float_as_int(x), 0x121, 0xF, 0xF, true)); // row_ror:1
    x += __int_as_float(__builtin_amdgcn_update_dpp(0, __float_as_int(x), 0x122, 0xF, 0xF, true)); // row_ror:2
    x += __int_as_float(__builtin_amdgcn_update_dpp(0, __float_as_int(x), 0x124, 0xF, 0xF, true)); // row_ror:4
    x += __int_as_float(__builtin_amdgcn_update_dpp(0, __float_as_int(x), 0x128, 0xF, 0xF, true)); // row_ror:8
    return x;
}

__device__ __forceinline__ float dot8(const float4 x0, const float4 x1,
                                      const float4 y0, const float4 y1)
{
    float a  = x0.x * y0.x;
    float b2 = x1.x * y1.x;
    a = fmaf(x0.y, y0.y, a); b2 = fmaf(x1.y, y1.y, b2);
    a = fmaf(x0.z, y0.z, a); b2 = fmaf(x1.z, y1.z, b2);
    a = fmaf(x0.w, y0.w, a); b2 = fmaf(x1.w, y1.w, b2);
    return a + b2;
}

// pack two fp32's top halves (truncate-to-bf16) into one u32: low16=bf16(a), high16=bf16(b)
__device__ __forceinline__ unsigned packhi2(unsigned a, unsigned b)
{
    return (b & 0xFFFF0000u) | (a >> 16);
}
__device__ __forceinline__ void split2(float a, float b, unsigned& hi, unsigned& lo)
{
    const unsigned ua = __float_as_uint(a), ub = __float_as_uint(b);
    const float la = a - __uint_as_float(ua & 0xFFFF0000u);
    const float lb = b - __uint_as_float(ub & 0xFFFF0000u);
    hi = packhi2(ua, ub);
    lo = packhi2(__float_as_uint(la), __float_as_uint(lb));
}

// -------- fused QKV MFMA GEMM (R7-validated, verbatim): [8192,1536] = x @ [Wq|Wk|Wv] ----
__global__ __launch_bounds__(256)
void gemm_qkv_mfma(const float* __restrict__ x,
                   const float* __restrict__ Wq, const float* __restrict__ Wk,
                   const float* __restrict__ Wv,
                   float* __restrict__ Qp, float* __restrict__ Kp, float* __restrict__ Vd)
{
    __shared__ __align__(16) unsigned short Ah[2][128][40];
    __shared__ __align__(16) unsigned short Al[2][128][40];
    __shared__ __align__(16) float          Bs[2][32][132];

    const int t    = threadIdx.x;
    const int l    = t & 63;
    const int wv   = t >> 6;
    const int wm   = wv >> 1;
    const int wn   = wv & 1;
    const int tx16 = l & 15;
    const int g4   = l >> 4;
    const int bm   = blockIdx.x * 128;
    const int grp  = blockIdx.y >> 2;          // 0=Q, 1=K, 2=V
    const int bn   = (blockIdx.y & 3) * 128;
    const float* W = (grp == 0) ? Wq : (grp == 1) ? Wk : Wv;

    f32x4 acc[4][4];
#pragma unroll
    for (int i = 0; i < 4; ++i)
#pragma unroll
        for (int j = 0; j < 4; ++j) acc[i][j] = 0.f;

    float4 xr[4], wr[4];

    auto loadA = [&](int kt) {
#pragma unroll
        for (int i = 0; i < 4; ++i) {
            const int L = t + i * 256;
            const int row = L >> 3, kq = (L & 7) << 2;
            xr[i] = *(const float4*)(x + (size_t)(bm + row) * 512 + kt * 32 + kq);
        }
    };
    auto writeA = [&](int buf) {
#pragma unroll
        for (int i = 0; i < 4; ++i) {
            const int L = t + i * 256;
            const int row = L >> 3, kq = (L & 7) << 2;
            const float4 v = xr[i];
            unsigned h0, l0, h1, l1;
            split2(v.x, v.y, h0, l0);
            split2(v.z, v.w, h1, l1);
            *(uint2*)&Ah[buf][row][kq] = make_uint2(h0, h1);
            *(uint2*)&Al[buf][row][kq] = make_uint2(l0, l1);
        }
    };
    auto loadB = [&](int kt) {
#pragma unroll
        for (int i = 0; i < 4; ++i) {
            const int L = t + i * 256;
            const int k = L >> 5, c4 = (L & 31) << 2;
            wr[i] = *(const float4*)(W + (size_t)(kt * 32 + k) * 512 + bn + c4);
        }
    };
    auto writeB = [&](int buf) {
#pragma unroll
        for (int i = 0; i < 4; ++i) {
            const int L = t + i * 256;
            const int k = L >> 5, c4 = (L & 31) << 2;
            *(float4*)&Bs[buf][k][c4] = wr[i];
        }
    };

    auto compute = [&](int buf) {
        s16x8 ah[4], al[4];
#pragma unroll
        for (int mf = 0; mf < 4; ++mf) {
            const int rowA = wm * 64 + mf * 16 + tx16;
            ah[mf] = *(const s16x8*)&Ah[buf][rowA][g4 * 8];
            al[mf] = *(const s16x8*)&Al[buf][rowA][g4 * 8];
        }
#pragma unroll
        for (int nf = 0; nf < 4; ++nf) {
            const int ncol = wn * 64 + nf * 16 + tx16;
            float bv[8];
#pragma unroll
            for (int i = 0; i < 8; ++i) bv[i] = Bs[buf][g4 * 8 + i][ncol];
            unsigned uh[4], ul[4];
#pragma unroll
            for (int w2 = 0; w2 < 4; ++w2)
                split2(bv[2 * w2], bv[2 * w2 + 1], uh[w2], ul[w2]);
            int4 bhv = make_int4(uh[0], uh[1], uh[2], uh[3]);
            int4 blv = make_int4(ul[0], ul[1], ul[2], ul[3]);
            const s16x8 bh = *(const s16x8*)&bhv;
            const s16x8 bl = *(const s16x8*)&blv;
#pragma unroll
            for (int mf = 0; mf < 4; ++mf) {
                acc[mf][nf] = __builtin_amdgcn_mfma_f32_16x16x32_bf16(ah[mf], bh, acc[mf][nf], 0, 0, 0);
                acc[mf][nf] = __builtin_amdgcn_mfma_f32_16x16x32_bf16(ah[mf], bl, acc[mf][nf], 0, 0, 0);
                acc[mf][nf] = __builtin_amdgcn_mfma_f32_16x16x32_bf16(al[mf], bh, acc[mf][nf], 0, 0, 0);
            }
        }
    };

    loadA(0); loadB(0); writeA(0); writeB(0);
    for (int kt = 0; kt < 16; ++kt) {
        const int buf = kt & 1;
        __syncthreads();
        if (kt < 15) { loadA(kt + 1); loadB(kt + 1); }
        compute(buf);
        if (kt < 15) { writeA(buf ^ 1); writeB(buf ^ 1); }
    }

    if (grp < 2) {
        float* dst = grp ? Kp : Qp;
        const int h = (blockIdx.y & 3) * 2 + wn;
        const int prevl = (l & 48) | ((l + 15) & 15);
#pragma unroll
        for (int mf = 0; mf < 4; ++mf) {
#pragma unroll
            for (int j = 0; j < 4; ++j) {
                float ap[4], an[4], sap[4], san[4];
#pragma unroll
                for (int nf = 0; nf < 4; ++nf) {
                    const float v = acc[mf][nf][j];
                    ap[nf] = fmaxf(v, 0.f);
                    an[nf] = fmaxf(-v, 0.f);
                }
#pragma unroll
                for (int nf = 0; nf < 4; ++nf) {
                    sap[nf] = __shfl(ap[nf], prevl);
                    san[nf] = __shfl(an[nf], prevl);
                }
                float y0[4], y1[4];
#pragma unroll
                for (int nf = 0; nf < 4; ++nf) {
                    const float pa = (tx16 == 0) ? (nf ? sap[nf - 1] : san[3]) : sap[nf];
                    const float pn = (tx16 == 0) ? (nf ? san[nf - 1] : sap[3]) : san[nf];
                    y0[nf] = ap[nf] * pa;
                    y1[nf] = an[nf] * pn;
                }
                float s = (y0[0] + y0[1] + y0[2] + y0[3]) + (y1[0] + y1[1] + y1[2] + y1[3]);
                s = rowsum16(s);
                const float inv = 1.f / (s + 1e-6f);
                const int m = bm + wm * 64 + mf * 16 + g4 * 4 + j;
#pragma unroll
                for (int nf = 0; nf < 4; ++nf) {
                    dst[(size_t)m * 1024 + h * 128 + nf * 16 + tx16]      = y0[nf] * inv;
                    dst[(size_t)m * 1024 + h * 128 + 64 + nf * 16 + tx16] = y1[nf] * inv;
                }
            }
        }
    } else {
#pragma unroll
        for (int mf = 0; mf < 4; ++mf) {
#pragma unroll
            for (int j = 0; j < 4; ++j) {
                const int m = bm + wm * 64 + mf * 16 + g4 * 4 + j;
#pragma unroll
                for (int nf = 0; nf < 4; ++nf) {
                    Vd[(size_t)m * 512 + (blockIdx.y & 3) * 128 + wn * 64 + nf * 16 + tx16] =
                        acc[mf][nf][j];
                }
            }
        }
    }
}

// -------- Wo MFMA GEMM: out[8192,512] = outs[8192,512] @ Wo + bo --------
// Direct port of the R7-validated gemm_qkv_mfma structure (same tiles, waves,
// fragment enumerations, split-bf16 3-MFMA math); B = Wo, bias epilogue.
// Grid (64, 4) = 256 blocks. Replaces the fp32-VALU gemm_wo (LDS-BW-bound).
__global__ __launch_bounds__(256)
void gemm_wo_mfma(const float* __restrict__ A, const float* __restrict__ Wo,
                  const float* __restrict__ bias, float* __restrict__ C)
{
    __shared__ __align__(16) unsigned short Ah[2][128][40];
    __shared__ __align__(16) unsigned short Al[2][128][40];
    __shared__ __align__(16) float          Bs[2][32][132];

    const int t    = threadIdx.x;
    const int l    = t & 63;
    const int wv   = t >> 6;
    const int wm   = wv >> 1;
    const int wn   = wv & 1;
    const int tx16 = l & 15;
    const int g4   = l >> 4;
    const int bm   = blockIdx.x * 128;
    const int bn   = blockIdx.y * 128;

    f32x4 acc[4][4];
#pragma unroll
    for (int i = 0; i < 4; ++i)
#pragma unroll
        for (int j = 0; j < 4; ++j) acc[i][j] = 0.f;

    float4 xr[4], wr[4];

    auto loadA = [&](int kt) {
#pragma unroll
        for (int i = 0; i < 4; ++i) {
            const int L = t + i * 256;
            const int row = L >> 3, kq = (L & 7) << 2;
            xr[i] = *(const float4*)(A + (size_t)(bm + row) * 512 + kt * 32 + kq);
        }
    };
    auto writeA = [&](int buf) {
#pragma unroll
        for (int i = 0; i < 4; ++i) {
            const int L = t + i * 256;
            const int row = L >> 3, kq = (L & 7) << 2;
            const float4 v = xr[i];
            unsigned h0, l0, h1, l1;
            split2(v.x, v.y, h0, l0);
            split2(v.z, v.w, h1, l1);
            *(uint2*)&Ah[buf][row][kq] = make_uint2(h0, h1);
            *(uint2*)&Al[buf][row][kq] = make_uint2(l0, l1);
        }
    };
    auto loadB = [&](int kt) {
#pragma unroll
        for (int i = 0; i < 4; ++i) {
            const int L = t + i * 256;
            const int k = L >> 5, c4 = (L & 31) << 2;
            wr[i] = *(const float4*)(Wo + (size_t)(kt * 32 + k) * 512 + bn + c4);
        }
    };
    auto writeB = [&](int buf) {
#pragma unroll
        for (int i = 0; i < 4; ++i) {
            const int L = t + i * 256;
            const int k = L >> 5, c4 = (L & 31) << 2;
            *(float4*)&Bs[buf][k][c4] = wr[i];
        }
    };

    auto compute = [&](int buf) {
        s16x8 ah[4], al[4];
#pragma unroll
        for (int mf = 0; mf < 4; ++mf) {
            const int rowA = wm * 64 + mf * 16 + tx16;
            ah[mf] = *(const s16x8*)&Ah[buf][rowA][g4 * 8];
            al[mf] = *(const s16x8*)&Al[buf][rowA][g4 * 8];
        }
#pragma unroll
        for (int nf = 0; nf < 4; ++nf) {
            const int ncol = wn * 64 + nf * 16 + tx16;
            float bv[8];
#pragma unroll
            for (int i = 0; i < 8; ++i) bv[i] = Bs[buf][g4 * 8 + i][ncol];
            unsigned uh[4], ul[4];
#pragma unroll
            for (int w2 = 0; w2 < 4; ++w2)
                split2(bv[2 * w2], bv[2 * w2 + 1], uh[w2], ul[w2]);
            int4 bhv = make_int4(uh[0], uh[1], uh[2], uh[3]);
            int4 blv = make_int4(ul[0], ul[1], ul[2], ul[3]);
            const s16x8 bh = *(const s16x8*)&bhv;
            const s16x8 bl = *(const s16x8*)&blv;
#pragma unroll
            for (int mf = 0; mf < 4; ++mf) {
                acc[mf][nf] = __builtin_amdgcn_mfma_f32_16x16x32_bf16(ah[mf], bh, acc[mf][nf], 0, 0, 0);
                acc[mf][nf] = __builtin_amdgcn_mfma_f32_16x16x32_bf16(ah[mf], bl, acc[mf][nf], 0, 0, 0);
                acc[mf][nf] = __builtin_amdgcn_mfma_f32_16x16x32_bf16(al[mf], bh, acc[mf][nf], 0, 0, 0);
            }
        }
    };

    loadA(0); loadB(0); writeA(0); writeB(0);
    for (int kt = 0; kt < 16; ++kt) {
        const int buf = kt & 1;
        __syncthreads();
        if (kt < 15) { loadA(kt + 1); loadB(kt + 1); }
        compute(buf);
        if (kt < 15) { writeA(buf ^ 1); writeB(buf ^ 1); }
    }

    float bvals[4];
#pragma unroll
    for (int nf = 0; nf < 4; ++nf)
        bvals[nf] = bias[bn + wn * 64 + nf * 16 + tx16];
#pragma unroll
    for (int mf = 0; mf < 4; ++mf) {
#pragma unroll
        for (int j = 0; j < 4; ++j) {
            const int m = bm + wm * 64 + mf * 16 + g4 * 4 + j;
#pragma unroll
            for (int nf = 0; nf < 4; ++nf) {
                C[(size_t)m * 512 + bn + wn * 64 + nf * 16 + tx16] =
                    acc[mf][nf][j] + bvals[nf];
            }
        }
    }
}

// ---------------- gate: beta = sigmoid(x @ Wg), whole sequence ----------------
__global__ __launch_bounds__(256)
void gemm_g_kernel(const float* __restrict__ X, const float* __restrict__ Wg,
                   float* __restrict__ Bt)
{
    const int idx = blockIdx.x * 256 + threadIdx.x;
    const int row = idx >> 3;
    const int c   = idx & 7;
    const float4* x4 = (const float4*)(X + (size_t)row * DMODEL);
    float acc = 0.f;
    for (int k4 = 0; k4 < 128; ++k4) {
        const float4 xv = x4[k4];
        acc = fmaf(xv.x, Wg[(k4 * 4 + 0) * 8 + c], acc);
        acc = fmaf(xv.y, Wg[(k4 * 4 + 1) * 8 + c], acc);
        acc = fmaf(xv.z, Wg[(k4 * 4 + 2) * 8 + c], acc);
        acc = fmaf(xv.w, Wg[(k4 * 4 + 3) * 8 + c], acc);
    }
    Bt[idx] = 1.f / (1.f + expf(-acc));
}

// ---------------- scan (R7-validated, verbatim except o-write is row-major) ----------
// 16 rows x 16 col-lanes, 256 blocks. 2-step look-ahead linearization, packed sd,
// ring-8 distance-4 register prefetch. The output line is the R0/R1-validated
// row-major form: outs[(g*BATCH+b)*DMODEL + h*DK + rg*16 + rloc] — so the Wo GEMM
// reads outs as a row-major NN A-operand (MFMA-friendly).
__global__ __launch_bounds__(256)
void scan_kernel(const float* __restrict__ Qp, const float* __restrict__ Kp,
                 const float* __restrict__ Vd, const float* __restrict__ Bt,
                 float* __restrict__ outs, float* __restrict__ Wst,
                 int s0, int first)
{
    const int blk = blockIdx.x;
    const int bh  = blk & 63;
    const int rg  = blk >> 6;
    const int b   = bh >> 3;
    const int h   = bh & 7;
    const int t   = threadIdx.x;
    const int c      = t & 15;     // col lane
    const int rloc   = t >> 4;     // row within group of 16
    const int wv  = t >> 6;        // wave id 0..3
    const int ln  = t & 63;        // lane within wave

    __shared__ __align__(16) float sk[2][SB][PHI];
    __shared__ __align__(16) float sq[2][SB][PHI];
    __shared__ __align__(16) float sv[2][SB][16];
    __shared__ __align__(16) float sb2[2][SB];
    __shared__ __align__(16) float sd[2][SB][4];   // {kk, kq1, kq0, beta}

    const size_t bh128 = (size_t)(b * 8 + h) * 128;

    float w[8];
    float* wslot = Wst + (size_t)blk * 2048 + t * 8;
    if (first) {
#pragma unroll
        for (int j = 0; j < 8; ++j) w[j] = 0.f;
    } else {
        const float4 w0 = *(const float4*)(wslot);
        const float4 w1 = *(const float4*)(wslot + 4);
        w[0] = w0.x; w[1] = w0.y; w[2] = w0.z; w[3] = w0.w;
        w[4] = w1.x; w[5] = w1.y; w[6] = w1.z; w[7] = w1.w;
    }

    auto stage = [&](int sbuf, int sb) {
        const int sqb = sb * SB;
        if (wv < 2) {
#pragma unroll
            for (int i = 0; i < 8; ++i) {
                const int L  = i * 128 + wv * 64 + ln;
                const int sl = L >> 5, c4 = L & 31;
                async16(Kp + (size_t)(sqb + sl) * 8192 + bh128 + c4 * 4,
                        &sk[sbuf][0][0] + L * 4);
            }
            {
                const int L  = wv * 64 + ln;
                const int sl = L >> 2, c4 = L & 3;
                async16(Vd + (size_t)(sqb + sl) * 4096 + b * 512 + h * 64 + rg * 16 + c4 * 4,
                        &sv[sbuf][0][0] + L * 4);
            }
        } else {
#pragma unroll
            for (int i = 0; i < 8; ++i) {
                const int L  = i * 128 + (wv - 2) * 64 + ln;
                const int sl = L >> 5, c4 = L & 31;
                async16(Qp + (size_t)(sqb + sl) * 8192 + bh128 + c4 * 4,
                        &sq[sbuf][0][0] + L * 4);
            }
            if (wv == 2 && ln < SB) {
                async4(Bt + (size_t)(s0 + sqb + ln) * 64 + b * 8 + h,
                       &sb2[sbuf][0] + ln);
            }
        }
    };

    auto dots_phase = [&](int buf, int sb) {
        const int sl0 = 2 * rloc;
        const float* kmp = (rloc == 0) ? &sk[buf ^ 1][SB - 1][0] : &sk[buf][sl0 - 1][0];
        const float4 km0 = *(const float4*)(kmp + 4 * c);
        const float4 km1 = *(const float4*)(kmp + 64 + 4 * c);
        const float4 ka0 = *(const float4*)&sk[buf][sl0][4 * c];
        const float4 ka1 = *(const float4*)&sk[buf][sl0][64 + 4 * c];
        const float4 kb0 = *(const float4*)&sk[buf][sl0 + 1][4 * c];
        const float4 kb1 = *(const float4*)&sk[buf][sl0 + 1][64 + 4 * c];
        const float4 qa0 = *(const float4*)&sq[buf][sl0][4 * c];
        const float4 qa1 = *(const float4*)&sq[buf][sl0][64 + 4 * c];
        const float4 qb0 = *(const float4*)&sq[buf][sl0 + 1][4 * c];
        const float4 qb1 = *(const float4*)&sq[buf][sl0 + 1][64 + 4 * c];
        const float kk_a  = rowsum16(dot8(km0, km1, ka0, ka1));
        const float kq1_a = rowsum16(dot8(km0, km1, qa0, qa1));
        const float kq0_a = rowsum16(dot8(ka0, ka1, qa0, qa1));
        const float kk_b  = rowsum16(dot8(ka0, ka1, kb0, kb1));
        const float kq1_b = rowsum16(dot8(ka0, ka1, qb0, qb1));
        const float kq0_b = rowsum16(dot8(kb0, kb1, qb0, qb1));
        if (c == 0) {
            const bool z = (sb == 0) && (rloc == 0);   // chunk's step 0: d_prev == 0
            sd[buf][sl0][0] = z ? 0.f : kk_a;
            sd[buf][sl0][1] = z ? 0.f : kq1_a;
            sd[buf][sl0][2] = kq0_a;
            sd[buf][sl0][3] = sb2[buf][sl0];
            sd[buf][sl0 + 1][0] = kk_b;
            sd[buf][sl0 + 1][1] = kq1_b;
            sd[buf][sl0 + 1][2] = kq0_b;
            sd[buf][sl0 + 1][3] = sb2[buf][sl0 + 1];
        }
    };

    struct Frag { float4 k0, k1, q0, q1; float bb, bv, kk, kq1, kq0; };
    Frag r[8];
    float d_prev = 0.f;

    auto preload = [&](Frag& f, int sbuf, int sl) {
        f.k0 = *(const float4*)&sk[sbuf][sl][4 * c];
        f.k1 = *(const float4*)&sk[sbuf][sl][64 + 4 * c];
        f.q0 = *(const float4*)&sq[sbuf][sl][4 * c];
        f.q1 = *(const float4*)&sq[sbuf][sl][64 + 4 * c];
        const float4 dd = *(const float4*)&sd[sbuf][sl][0];
        f.kk = dd.x; f.kq1 = dd.y; f.kq0 = dd.z; f.bb = dd.w;
        f.bv = f.bb * sv[sbuf][sl][rloc];
    };

    auto step_compute = [&](const Frag& f, const Frag& fp, int g) {
        float A0 = w[0] * f.k0.x;
        float A1 = w[4] * f.k1.x;
        A0 = fmaf(w[1], f.k0.y, A0); A1 = fmaf(w[5], f.k1.y, A1);
        A0 = fmaf(w[2], f.k0.z, A0); A1 = fmaf(w[6], f.k1.z, A1);
        A0 = fmaf(w[3], f.k0.w, A0); A1 = fmaf(w[7], f.k1.w, A1);
        float Q0 = w[0] * f.q0.x;
        float Q1 = w[4] * f.q1.x;
        Q0 = fmaf(w[1], f.q0.y, Q0); Q1 = fmaf(w[5], f.q1.y, Q1);
        Q0 = fmaf(w[2], f.q0.z, Q0); Q1 = fmaf(w[6], f.q1.z, Q1);
        Q0 = fmaf(w[3], f.q0.w, Q0); Q1 = fmaf(w[7], f.q1.w, Q1);
        const float Ar  = rowsum16(A0 + A1);
        const float Aqr = rowsum16(Q0 + Q1);
        w[0] = fmaf(d_prev, fp.k0.x, w[0]);
        w[1] = fmaf(d_prev, fp.k0.y, w[1]);
        w[2] = fmaf(d_prev, fp.k0.z, w[2]);
        w[3] = fmaf(d_prev, fp.k0.w, w[3]);
        w[4] = fmaf(d_prev, fp.k1.x, w[4]);
        w[5] = fmaf(d_prev, fp.k1.y, w[5]);
        w[6] = fmaf(d_prev, fp.k1.z, w[6]);
        w[7] = fmaf(d_prev, fp.k1.w, w[7]);
        const float a = fmaf(d_prev, f.kk, Ar);
        const float d = fmaf(-f.bb, a, f.bv);
        float o = fmaf(d_prev, f.kq1, Aqr);
        o = fmaf(d, f.kq0, o);
        if (c == 0)
            outs[(size_t)(g * BATCH + b) * DMODEL + h * DK + rg * 16 + rloc] = o;
        d_prev = d;
    };

    r[7].k0 = make_float4(0.f, 0.f, 0.f, 0.f);
    r[7].k1 = make_float4(0.f, 0.f, 0.f, 0.f);

    stage(0, 0);
    for (int sb = 0; sb < NSB; ++sb) {
        const int buf = sb & 1;
        __syncthreads();                     // staged loads for buf complete
        dots_phase(buf, sb);
        __syncthreads();                     // sd visible; prev-buffer boundary reads done
        if (sb + 1 < NSB) stage(buf ^ 1, sb + 1);
        preload(r[0], buf, 0);
        preload(r[1], buf, 1);
        preload(r[2], buf, 2);
        preload(r[3], buf, 3);
#pragma unroll
        for (int s = 0; s < SB; ++s) {
            if (s + 4 < SB) preload(r[(s + 4) & 7], buf, s + 4);   // distance-4 prefetch
            step_compute(r[s & 7], r[(s + 7) & 7], sb * SB + s);
        }
    }

    // apply the pending final update (step 1023 -> ring slot 7)
    w[0] = fmaf(d_prev, r[7].k0.x, w[0]);
    w[1] = fmaf(d_prev, r[7].k0.y, w[1]);
    w[2] = fmaf(d_prev, r[7].k0.z, w[2]);
    w[3] = fmaf(d_prev, r[7].k0.w, w[3]);
    w[4] = fmaf(d_prev, r[7].k1.x, w[4]);
    w[5] = fmaf(d_prev, r[7].k1.y, w[5]);
    w[6] = fmaf(d_prev, r[7].k1.z, w[6]);
    w[7] = fmaf(d_prev, r[7].k1.w, w[7]);

    float4 w0, w1;
    w0.x = w[0]; w0.y = w[1]; w0.z = w[2]; w0.w = w[3];
    w1.x = w[4]; w1.y = w[5]; w1.z = w[6]; w1.w = w[7];
    *(float4*)(wslot)     = w0;
    *(float4*)(wslot + 4) = w1;
}

extern "C" void kernel_launch(void* const* d_in, const int* in_sizes, int n_in,
                              void* d_out, int out_size, void* d_ws, size_t ws_size,
                              hipStream_t stream)
{
    const float* x  = (const float*)d_in[0];
    const float* Wq = (const float*)d_in[1];
    const float* Wk = (const float*)d_in[2];
    const float* Wv = (const float*)d_in[3];
    const float* Wg = (const float*)d_in[4];
    const float* Wo = (const float*)d_in[5];
    const float* bo = (const float*)d_in[6];
    float* out = (float*)d_out;

    // workspace (floats), ~104 MB (R7 layout). tmp = scan outs [8192][512] row-major.
    float* ws  = (float*)d_ws;
    float* tmp = ws;                                   // [8192][512]  (scan outs)
    float* Qp  = ws  + (size_t)512 * CROWS;            // [8192][1024]
    float* Kp  = Qp  + (size_t)CROWS * 1024;           // [8192][1024]
    float* Vd  = Kp  + (size_t)CROWS * 1024;           // [8192][512]
    float* Bt  = Vd  + (size_t)CROWS * 512;            // [32768][8]
    float* Wst = Bt  + (size_t)(SEQ * BATCH) * 8;      // [256][2048]
    (void)in_sizes; (void)n_in; (void)out_size; (void)ws_size;

    const dim3 gq(CROWS / 128, 12);            // (64, 12) fused QKV
    const dim3 go(CROWS / 128, DMODEL / 128);  // (64, 4)  Wo MFMA
    const int NCH = SEQ / CHUNK;               // 4

    gemm_g_kernel<<<(SEQ * BATCH * 8) / 256, 256, 0, stream>>>(x, Wg, Bt);

    for (int c = 0; c < NCH; ++c) {
        const float* xc = x + (size_t)c * CROWS * DMODEL;
        gemm_qkv_mfma<<<gq, 256, 0, stream>>>(xc, Wq, Wk, Wv, Qp, Kp, Vd);
        scan_kernel<<<256, 256, 0, stream>>>(Qp, Kp, Vd, Bt, tmp, Wst,
                                             c * CHUNK, c == 0 ? 1 : 0);
        gemm_wo_mfma<<<go, 256, 0, stream>>>(tmp, Wo, bo,
                                             out + (size_t)c * CROWS * DMODEL);
    }
}